// Round 7
// baseline (876.713 us; speedup 1.0000x reference)
//
#include <hip/hip_runtime.h>
#include <hip/hip_bf16.h>
#include <stdint.h>

#define BB 2
#define TT 2048
#define DD 1024
#define NH 16
#define HD 64
#define TOPK 64
#define NEGF (-3.402823466e38f)
#define ORD_NEG 0x00800000u  // ord_u32(NEGF)
#define QT 16                // q-rows per block (1 per wave)
#define KT 256               // keys per tile
#define SELCAP 96

typedef short short8x __attribute__((ext_vector_type(8)));
typedef float floatx4 __attribute__((ext_vector_type(4)));

// ---------- helpers ----------
__device__ __forceinline__ uint32_t ord_u32(float x) {
    uint32_t b = __float_as_uint(x);
    return (b & 0x80000000u) ? ~b : (b | 0x80000000u);
}
__device__ __forceinline__ float unord(uint32_t u) {
    uint32_t b = (u & 0x80000000u) ? (u ^ 0x80000000u) : ~u;
    return __uint_as_float(b);
}
__device__ __forceinline__ short bf16_rne(float x) {
    uint32_t u = __float_as_uint(x);
    u += 0x7FFFu + ((u >> 16) & 1u);
    return (short)(u >> 16);
}
__device__ __forceinline__ float bf16_to_f(short h) {
    return __uint_as_float(((uint32_t)(uint16_t)h) << 16);
}
__device__ __forceinline__ bool mask_at(const void* m, int mode, int idx) {
    if (mode == 0) return ((const int*)m)[idx] != 0;
    if (mode == 1) return ((const unsigned char*)m)[idx] != 0;
    return ((const float*)m)[idx] != 0.0f;
}

// ---------- DPP wave-64 reductions ----------
__device__ __forceinline__ int dpp_wsum(int v) {
    v += __builtin_amdgcn_update_dpp(0, v, 0x111, 0xf, 0xf, true);
    v += __builtin_amdgcn_update_dpp(0, v, 0x112, 0xf, 0xf, true);
    v += __builtin_amdgcn_update_dpp(0, v, 0x114, 0xf, 0xf, true);
    v += __builtin_amdgcn_update_dpp(0, v, 0x118, 0xf, 0xf, true);
    v += __builtin_amdgcn_update_dpp(0, v, 0x142, 0xa, 0xf, true);
    v += __builtin_amdgcn_update_dpp(0, v, 0x143, 0xc, 0xf, true);
    return __builtin_amdgcn_readlane(v, 63);
}
__device__ __forceinline__ uint32_t dpp_wumax(uint32_t v) {
    uint32_t t;
    t = (uint32_t)__builtin_amdgcn_update_dpp(0, (int)v, 0x111, 0xf, 0xf, true); v = v > t ? v : t;
    t = (uint32_t)__builtin_amdgcn_update_dpp(0, (int)v, 0x112, 0xf, 0xf, true); v = v > t ? v : t;
    t = (uint32_t)__builtin_amdgcn_update_dpp(0, (int)v, 0x114, 0xf, 0xf, true); v = v > t ? v : t;
    t = (uint32_t)__builtin_amdgcn_update_dpp(0, (int)v, 0x118, 0xf, 0xf, true); v = v > t ? v : t;
    t = (uint32_t)__builtin_amdgcn_update_dpp(0, (int)v, 0x142, 0xa, 0xf, true); v = v > t ? v : t;
    t = (uint32_t)__builtin_amdgcn_update_dpp(0, (int)v, 0x143, 0xc, 0xf, true); v = v > t ? v : t;
    return (uint32_t)__builtin_amdgcn_readlane((int)v, 63);
}
__device__ __forceinline__ float dpp_fsum(float v) {
    v += __uint_as_float((uint32_t)__builtin_amdgcn_update_dpp(0, (int)__float_as_uint(v), 0x111, 0xf, 0xf, true));
    v += __uint_as_float((uint32_t)__builtin_amdgcn_update_dpp(0, (int)__float_as_uint(v), 0x112, 0xf, 0xf, true));
    v += __uint_as_float((uint32_t)__builtin_amdgcn_update_dpp(0, (int)__float_as_uint(v), 0x114, 0xf, 0xf, true));
    v += __uint_as_float((uint32_t)__builtin_amdgcn_update_dpp(0, (int)__float_as_uint(v), 0x118, 0xf, 0xf, true));
    v += __uint_as_float((uint32_t)__builtin_amdgcn_update_dpp(0, (int)__float_as_uint(v), 0x142, 0xa, 0xf, true));
    v += __uint_as_float((uint32_t)__builtin_amdgcn_update_dpp(0, (int)__float_as_uint(v), 0x143, 0xc, 0xf, true));
    return __uint_as_float((uint32_t)__builtin_amdgcn_readlane((int)__float_as_uint(v), 63));
}

// ---------- mask detection + transposed bitmask build ----------
__global__ void __launch_bounds__(1024) build_flags(
    const unsigned char* raw, const int* causalp, int* flags, uint32_t* Mt)
{
    __shared__ int odd_nz, big, s_mode;
    __shared__ uint32_t smt[BB * 64];
    const int tid = threadIdx.x;
    if (tid == 0) { odd_nz = 0; big = 0; }
    if (tid < BB * 64) smt[tid] = 0;
    __syncthreads();
    for (int i = tid; i < BB * TT; i += 1024) {
        unsigned char c = raw[i];
        if ((i & 3) && c) atomicOr(&odd_nz, 1);
        if (c > 1) atomicOr(&big, 1);
    }
    __syncthreads();
    if (tid == 0) {
        int mode = odd_nz ? (big ? 2 : 1) : 0;
        s_mode = mode;
        flags[0] = mode;
        flags[1] = (causalp[0] != 0) ? 1 : 0;
    }
    __syncthreads();
    const int mode = s_mode;
    const int w = tid >> 3, g = tid & 7;
    const int bb = w >> 6, l = w & 63;
    uint32_t bits = 0;
#pragma unroll
    for (int si = 0; si < 4; ++si) {
        int s = g * 4 + si;
        if (mask_at(raw, mode, bb * TT + l + 64 * s)) bits |= (1u << s);
    }
    if (bits) atomicOr(&smt[w], bits);
    __syncthreads();
    if (tid < BB * 64) Mt[tid] = smt[tid];
}

// ---------- f32 -> (hi, lo) bf16 split (with scale) ----------
__global__ void __launch_bounds__(256) split_f32(
    const float* __restrict__ in, short* __restrict__ hi, short* __restrict__ lo,
    int n4, float scale)
{
    int i = blockIdx.x * blockDim.x + threadIdx.x;
    if (i >= n4) return;
    float4 v = ((const float4*)in)[i];
    float f[4] = {v.x * scale, v.y * scale, v.z * scale, v.w * scale};
    short hh[4], ll[4];
#pragma unroll
    for (int j = 0; j < 4; ++j) {
        hh[j] = bf16_rne(f[j]);
        ll[j] = bf16_rne(f[j] - bf16_to_f(hh[j]));
    }
    short4 h4; h4.x = hh[0]; h4.y = hh[1]; h4.z = hh[2]; h4.w = hh[3];
    short4 l4; l4.x = ll[0]; l4.y = ll[1]; l4.z = ll[2]; l4.w = ll[3];
    ((short4*)hi)[i] = h4;
    ((short4*)lo)[i] = l4;
}

// ---------- 4 weights split in one launch ----------
__global__ void __launch_bounds__(256) split_w4(
    const float* __restrict__ W0, const float* __restrict__ W1,
    const float* __restrict__ W2, const float* __restrict__ W3,
    short* __restrict__ h0, short* __restrict__ l0, short* __restrict__ h1, short* __restrict__ l1,
    short* __restrict__ h2, short* __restrict__ l2, short* __restrict__ h3, short* __restrict__ l3,
    int n4)
{
    int i = blockIdx.x * blockDim.x + threadIdx.x;
    if (i >= n4) return;
    const int w = blockIdx.y;
    const float* in = (w == 0) ? W0 : (w == 1) ? W1 : (w == 2) ? W2 : W3;
    short* hi = (w == 0) ? h0 : (w == 1) ? h1 : (w == 2) ? h2 : h3;
    short* lo = (w == 0) ? l0 : (w == 1) ? l1 : (w == 2) ? l2 : l3;
    float4 v = ((const float4*)in)[i];
    float f[4] = {v.x, v.y, v.z, v.w};
    short hh[4], ll[4];
#pragma unroll
    for (int j = 0; j < 4; ++j) {
        hh[j] = bf16_rne(f[j]);
        ll[j] = bf16_rne(f[j] - bf16_to_f(hh[j]));
    }
    short4 h4; h4.x = hh[0]; h4.y = hh[1]; h4.z = hh[2]; h4.w = hh[3];
    short4 l4; l4.x = ll[0]; l4.y = ll[1]; l4.z = ll[2]; l4.w = ll[3];
    ((short4*)hi)[i] = h4;
    ((short4*)lo)[i] = l4;
}

// ---------- split-bf16 MFMA GEMM, 64x64 tile (4 waves), dbuf prefetch ----------
// mode 0: f32 row-major; mode 1: f32 split-heads; mode 2: bf16 hi/lo split-heads (scaled)
__global__ void __launch_bounds__(256) gemm_bf16s(
    const short* __restrict__ Ah, const short* __restrict__ Al,
    const short* __restrict__ Bh, const short* __restrict__ Bl,
    const float* __restrict__ bias, float* __restrict__ Cf,
    short* __restrict__ Ch, short* __restrict__ Cl, float scale, int mode)
{
    const int tid = threadIdx.x, lane = tid & 63, wv = tid >> 6;  // 4 waves
    const int m0 = blockIdx.y * 64 + (wv >> 1) * 32;
    const int n0 = blockIdx.x * 64 + (wv & 1) * 32;
    const int lrow = lane & 15, lk = (lane >> 4) * 8;

    floatx4 acc[2][2];
#pragma unroll
    for (int i = 0; i < 2; ++i)
#pragma unroll
        for (int j = 0; j < 2; ++j) acc[i][j] = (floatx4){0.f, 0.f, 0.f, 0.f};

    auto ldfr = [&](int kk, short8x* pah, short8x* pal, short8x* pbh, short8x* pbl) {
#pragma unroll
        for (int mb = 0; mb < 2; ++mb) {
            size_t off = (size_t)(m0 + mb * 16 + lrow) * DD + kk + lk;
            pah[mb] = *(const short8x*)(Ah + off);
            pal[mb] = *(const short8x*)(Al + off);
        }
#pragma unroll
        for (int nb = 0; nb < 2; ++nb) {
            size_t off = (size_t)(n0 + nb * 16 + lrow) * DD + kk + lk;
            pbh[nb] = *(const short8x*)(Bh + off);
            pbl[nb] = *(const short8x*)(Bl + off);
        }
    };
    auto domfma = [&](short8x* pah, short8x* pal, short8x* pbh, short8x* pbl) {
#pragma unroll
        for (int mb = 0; mb < 2; ++mb)
#pragma unroll
            for (int nb = 0; nb < 2; ++nb) {
                acc[mb][nb] = __builtin_amdgcn_mfma_f32_16x16x32_bf16(pah[mb], pbh[nb], acc[mb][nb], 0, 0, 0);
                acc[mb][nb] = __builtin_amdgcn_mfma_f32_16x16x32_bf16(pah[mb], pbl[nb], acc[mb][nb], 0, 0, 0);
                acc[mb][nb] = __builtin_amdgcn_mfma_f32_16x16x32_bf16(pal[mb], pbh[nb], acc[mb][nb], 0, 0, 0);
            }
    };

    short8x A0[2], L0[2], B0[2], C0[2];
    short8x A1[2], L1[2], B1[2], C1[2];
    ldfr(0, A0, L0, B0, C0);
    for (int kk = 0; kk < DD; kk += 64) {
        ldfr(kk + 32, A1, L1, B1, C1);
        domfma(A0, L0, B0, C0);
        if (kk + 64 < DD) ldfr(kk + 64, A0, L0, B0, C0);
        domfma(A1, L1, B1, C1);
    }

#pragma unroll
    for (int mb = 0; mb < 2; ++mb)
#pragma unroll
        for (int nb = 0; nb < 2; ++nb) {
            int n = n0 + nb * 16 + lrow;
            float bv = bias[n];
#pragma unroll
            for (int j = 0; j < 4; ++j) {
                int m = m0 + mb * 16 + (lane >> 4) * 4 + j;
                float v = acc[mb][nb][j] + bv;
                if (mode == 0) {
                    Cf[(size_t)m * DD + n] = v;
                } else {
                    int b = m >> 11, t = m & (TT - 1), h = n >> 6, dh = n & (HD - 1);
                    size_t idx = (((size_t)b * NH + h) * TT + t) * HD + dh;
                    if (mode == 1) {
                        Cf[idx] = v;
                    } else {
                        v *= scale;
                        short hi16 = bf16_rne(v);
                        Ch[idx] = hi16;
                        Cl[idx] = bf16_rne(v - bf16_to_f(hi16));
                    }
                }
            }
        }
}

// ---------- f32 GEMM (fallback) ----------
__global__ void __launch_bounds__(256) gemm_xwt(
    const float* __restrict__ A, const float* __restrict__ W,
    const float* __restrict__ bias, float* __restrict__ C,
    int M, int N, int K, int split_heads)
{
    __shared__ float As[64][17];
    __shared__ float Ws[64][17];
    const int tid = threadIdx.x;
    const int tx = tid & 15, ty = tid >> 4;
    const int arow = blockIdx.y * 64, bcol = blockIdx.x * 64;
    float acc[4][4] = {};

    for (int k0 = 0; k0 < K; k0 += 16) {
        const int r = tid >> 2, c = (tid & 3) * 4;
        float4 a4 = *(const float4*)(A + (size_t)(arow + r) * K + k0 + c);
        As[r][c] = a4.x; As[r][c + 1] = a4.y; As[r][c + 2] = a4.z; As[r][c + 3] = a4.w;
        float4 w4 = *(const float4*)(W + (size_t)(bcol + r) * K + k0 + c);
        Ws[r][c] = w4.x; Ws[r][c + 1] = w4.y; Ws[r][c + 2] = w4.z; Ws[r][c + 3] = w4.w;
        __syncthreads();
#pragma unroll
        for (int k = 0; k < 16; ++k) {
            float a0 = As[ty * 4 + 0][k], a1 = As[ty * 4 + 1][k];
            float a2 = As[ty * 4 + 2][k], a3 = As[ty * 4 + 3][k];
            float w0 = Ws[tx * 4 + 0][k], w1 = Ws[tx * 4 + 1][k];
            float w2 = Ws[tx * 4 + 2][k], w3 = Ws[tx * 4 + 3][k];
            acc[0][0] += a0 * w0; acc[0][1] += a0 * w1; acc[0][2] += a0 * w2; acc[0][3] += a0 * w3;
            acc[1][0] += a1 * w0; acc[1][1] += a1 * w1; acc[1][2] += a1 * w2; acc[1][3] += a1 * w3;
            acc[2][0] += a2 * w0; acc[2][1] += a2 * w1; acc[2][2] += a2 * w2; acc[2][3] += a2 * w3;
            acc[3][0] += a3 * w0; acc[3][1] += a3 * w1; acc[3][2] += a3 * w2; acc[3][3] += a3 * w3;
        }
        __syncthreads();
    }

#pragma unroll
    for (int i = 0; i < 4; ++i) {
        int m = arow + ty * 4 + i;
#pragma unroll
        for (int j = 0; j < 4; ++j) {
            int n = bcol + tx * 4 + j;
            float v = acc[i][j] + bias[n];
            if (split_heads) {
                int b = m / TT, t = m % TT, h = n / HD, dh = n % HD;
                C[(((size_t)b * NH + h) * TT + t) * HD + dh] = v;
            } else {
                C[(size_t)m * N + n] = v;
            }
        }
    }
}

// ---------- MFMA attention with exact register-resident top-64 ----------
// XCD-swizzled 1D grid: each XCD owns 4 heads -> K/V stay L2-resident.
__global__ void __launch_bounds__(1024) attn_topk(
    const short* __restrict__ Qhi, const short* __restrict__ Qlo,
    const short* __restrict__ Khi, const short* __restrict__ Klo,
    const float* __restrict__ V, const uint32_t* __restrict__ Mt,
    const int* __restrict__ flags, short* __restrict__ Ohi,
    short* __restrict__ Olo, float* __restrict__ Of)
{
    __shared__ float s_S[2][QT][KT + 1];     // 32.9 KB (double-buffered)
    __shared__ int2  s_sel[QT][SELCAP];      // packed (key<<6, w bits)

    const int tid = threadIdx.x, lane = tid & 63, wv = tid >> 6;
    const int d = blockIdx.x;                // 0..4095, XCD = d & 7 (round-robin)
    const int xcd = d & 7, chunk = d >> 3;
    const int bh = (xcd << 2) | (chunk >> 7);  // 4 heads per XCD
    const int qt = chunk & 127;
    const int b = bh >> 4, h = bh & 15;
    const int causal = flags[1];
    const size_t hb = (size_t)bh * (size_t)TT * HD;
    const int r0 = qt * QT;
    const int gq = r0 + wv;
    const float* __restrict__ Vh = V + hb;
    const float* __restrict__ Vl = Vh + lane;

    short8x qhi[2], qlo[2];
    {
        const size_t qoff = hb + (size_t)(r0 + (lane & 15)) * HD + (lane >> 4) * 8;
        qhi[0] = *(const short8x*)(Qhi + qoff);
        qhi[1] = *(const short8x*)(Qhi + qoff + 32);
        qlo[0] = *(const short8x*)(Qlo + qoff);
        qlo[1] = *(const short8x*)(Qlo + qoff + 32);
    }

    const uint32_t mwords = Mt[b * 64 + lane];

    uint32_t lgo[32];
#pragma unroll
    for (int i = 0; i < 32; ++i) lgo[i] = ORD_NEG;

    const int lastT = causal ? ((r0 + QT - 1) >> 8) : 7;

#pragma unroll
    for (int t = 0; t < 8; ++t) {
        if (t <= lastT) {
            const size_t koff = hb + (size_t)(t * KT + wv * 16 + (lane & 15)) * HD + (lane >> 4) * 8;
            short8x kh0 = *(const short8x*)(Khi + koff);
            short8x kh1 = *(const short8x*)(Khi + koff + 32);
            short8x kl0 = *(const short8x*)(Klo + koff);
            short8x kl1 = *(const short8x*)(Klo + koff + 32);
            floatx4 acc = {0.f, 0.f, 0.f, 0.f};
            acc = __builtin_amdgcn_mfma_f32_16x16x32_bf16(qhi[0], kh0, acc, 0, 0, 0);
            acc = __builtin_amdgcn_mfma_f32_16x16x32_bf16(qhi[0], kl0, acc, 0, 0, 0);
            acc = __builtin_amdgcn_mfma_f32_16x16x32_bf16(qlo[0], kh0, acc, 0, 0, 0);
            acc = __builtin_amdgcn_mfma_f32_16x16x32_bf16(qhi[1], kh1, acc, 0, 0, 0);
            acc = __builtin_amdgcn_mfma_f32_16x16x32_bf16(qhi[1], kl1, acc, 0, 0, 0);
            acc = __builtin_amdgcn_mfma_f32_16x16x32_bf16(qlo[1], kh1, acc, 0, 0, 0);
#pragma unroll
            for (int j = 0; j < 4; ++j)
                s_S[t & 1][(lane >> 4) * 4 + j][wv * 16 + (lane & 15)] = acc[j];
            __syncthreads();
#pragma unroll
            for (int j = 0; j < 4; ++j) {
                float sv = s_S[t & 1][wv][j * 64 + lane];
                int key = t * KT + j * 64 + lane;
                bool blocked = ((mwords >> (t * 4 + j)) & 1u) || (causal && key > gq);
                lgo[t * 4 + j] = blocked ? ORD_NEG : ord_u32(sv);
            }
        }
    }

    // ---- epilogue: exact top-64 select + softmax + sparse A*V ----
    uint32_t moL = 0; int nvL = 0;
#pragma unroll
    for (int i = 0; i < 32; ++i) {
        uint32_t u = lgo[i];
        moL = u > moL ? u : moL;
        nvL += (u > ORD_NEG) ? 1 : 0;
    }
    const uint32_t mo = dpp_wumax(moL);
    const int nv = dpp_wsum(nvL);

    auto wcount = [&](uint32_t thrv) -> int {
        int c = 0;
#pragma unroll
        for (int i = 0; i < 32; ++i) c += (lgo[i] >= thrv) ? 1 : 0;
        return dpp_wsum(c);
    };

    float outv;
    if (nv == 0) {
        // fully blocked row: reference softmax is uniform over ALL keys
        float a0 = 0.f, a1 = 0.f, a2 = 0.f, a3 = 0.f;
        for (int j = 0; j < TT; j += 4) {
            a0 += Vh[(j + 0) * HD + lane];
            a1 += Vh[(j + 1) * HD + lane];
            a2 += Vh[(j + 2) * HD + lane];
            a3 += Vh[(j + 3) * HD + lane];
        }
        outv = (a0 + a1 + a2 + a3) * (1.0f / TT);
    } else {
        const float mF = unord(mo);
        uint32_t thr = 0; uint32_t lo_b = 0, hi_b = 0; int done = 0;
        {
            uint32_t p1 = ord_u32(mF - 2.0f);
            int c1 = wcount(p1);
            if (c1 == TOPK) { thr = p1; done = 1; }
            else if (c1 > TOPK) { lo_b = p1; hi_b = mo; }
            else {
                uint32_t p2 = ord_u32(mF - 4.0f);
                int c2 = wcount(p2);
                if (c2 == TOPK) { thr = p2; done = 1; }
                else if (c2 > TOPK) { lo_b = p2; hi_b = p1; }
                else {
                    uint32_t p3 = ord_u32(mF - 15.0f);
                    int c3 = wcount(p3);
                    if (c3 <= TOPK) { thr = p3; done = 1; }  // <64 candidates: rest < e^-15
                    else { lo_b = p3; hi_b = p2; }
                }
            }
        }
        if (!done) {
            while (hi_b - lo_b > 1u) {
                uint32_t mid = lo_b + ((hi_b - lo_b) >> 1);
                int c = wcount(mid);
                if (c == TOPK) { lo_b = mid; break; }
                if (c > TOPK) lo_b = mid; else hi_b = mid;
            }
            thr = lo_b;
        }

        int dummy = 0; (void)dummy;
        float Sp = 0.f;
#pragma unroll
        for (int i = 0; i < 32; ++i) {
            uint32_t u = lgo[i];
            float w = 0.f;
            if (u >= thr) w = __expf(unord(u) - mF);
            Sp += w;
            lgo[i] = (w > 0.f) ? __float_as_uint(w) : 0u;
        }
        const float S = dpp_fsum(Sp);

        // ballot/mbcnt compaction (no scan, no atomics)
        int base = 0;
#pragma unroll
        for (int i = 0; i < 32; ++i) {
            uint32_t wbits = lgo[i];
            unsigned long long msk = __ballot(wbits != 0);
            if (wbits) {
                int below = __builtin_amdgcn_mbcnt_hi((uint32_t)(msk >> 32),
                            __builtin_amdgcn_mbcnt_lo((uint32_t)msk, 0));
                int pos = base + below;
                if (pos < SELCAP) {
                    int keyoff = (((i >> 2) * KT + (i & 3) * 64 + lane) << 6);
                    s_sel[wv][pos] = make_int2(keyoff, (int)wbits);
                }
            }
            base += (int)__popcll(msk);
        }
        int cnt = base < SELCAP ? base : SELCAP;

        // sparse A*V: scalar (readfirstlane) key base -> coalesced V row reads
        float acc = 0.f;
        int i2 = 0;
        for (; i2 + 4 <= cnt; i2 += 4) {
            int2 e0 = s_sel[wv][i2],     e1 = s_sel[wv][i2 + 1];
            int2 e2 = s_sel[wv][i2 + 2], e3 = s_sel[wv][i2 + 3];
            int k0 = __builtin_amdgcn_readfirstlane(e0.x);
            int k1 = __builtin_amdgcn_readfirstlane(e1.x);
            int k2 = __builtin_amdgcn_readfirstlane(e2.x);
            int k3 = __builtin_amdgcn_readfirstlane(e3.x);
            float w0 = __uint_as_float((uint32_t)__builtin_amdgcn_readfirstlane(e0.y));
            float w1 = __uint_as_float((uint32_t)__builtin_amdgcn_readfirstlane(e1.y));
            float w2 = __uint_as_float((uint32_t)__builtin_amdgcn_readfirstlane(e2.y));
            float w3 = __uint_as_float((uint32_t)__builtin_amdgcn_readfirstlane(e3.y));
            acc += w0 * Vl[k0];
            acc += w1 * Vl[k1];
            acc += w2 * Vl[k2];
            acc += w3 * Vl[k3];
        }
        for (; i2 < cnt; ++i2) {
            int2 e = s_sel[wv][i2];
            int k = __builtin_amdgcn_readfirstlane(e.x);
            float w = __uint_as_float((uint32_t)__builtin_amdgcn_readfirstlane(e.y));
            acc += w * Vl[k];
        }
        outv = acc / S;
    }
    const size_t oidx = ((size_t)b * TT + gq) * DD + h * HD + lane;
    if (Of) {
        Of[oidx] = outv;
    } else {
        short hi16 = bf16_rne(outv);
        Ohi[oidx] = hi16;
        Olo[oidx] = bf16_rne(outv - bf16_to_f(hi16));
    }
}

// ---------- launch ----------
extern "C" void kernel_launch(void* const* d_in, const int* in_sizes, int n_in,
                              void* d_out, int out_size, void* d_ws, size_t ws_size,
                              hipStream_t stream) {
    const float* x  = (const float*)d_in[0];
    const float* Wq = (const float*)d_in[1];
    const float* bq = (const float*)d_in[2];
    const float* Wk = (const float*)d_in[3];
    const float* bk = (const float*)d_in[4];
    const float* Wv = (const float*)d_in[5];
    const float* bv = (const float*)d_in[6];
    const float* Wo = (const float*)d_in[7];
    const float* bo = (const float*)d_in[8];
    const void*  maskp = d_in[9];
    const int*   causalp = (const int*)d_in[10];
    float* out = (float*)d_out;

    char* ws = (char*)d_ws;
    const size_t TEN  = (size_t)BB * TT * DD * sizeof(float);  // 16.78 MB
    const size_t HTEN = TEN / 2;
    const size_t WSZ  = (size_t)DD * DD * 2;                   // 2 MB bf16 weight
    const size_t NEED = 6 * TEN + 4096;

    const int nx4 = BB * TT * DD / 4, nw4 = DD * DD / 4;
    dim3 gg(DD / 64, (BB * TT) / 64);   // 64x64 tiles -> 1024 blocks

    if (ws_size >= NEED) {
        float* Vf   = (float*)(ws);
        short* xh   = (short*)(ws + TEN);
        short* xl   = (short*)(ws + TEN + HTEN);
        short* Qhi  = (short*)(ws + 2 * TEN);
        short* Qlo  = (short*)(ws + 2 * TEN + HTEN);
        short* Khi  = (short*)(ws + 3 * TEN);
        short* Klo  = (short*)(ws + 3 * TEN + HTEN);
        short* Ohi  = (short*)(ws + 4 * TEN);
        short* Olo  = (short*)(ws + 4 * TEN + HTEN);
        char*  wb   = ws + 5 * TEN;
        short* wqh = (short*)(wb);            short* wql = (short*)(wb + WSZ);
        short* wkh = (short*)(wb + 2 * WSZ);  short* wkl = (short*)(wb + 3 * WSZ);
        short* wvh = (short*)(wb + 4 * WSZ);  short* wvl = (short*)(wb + 5 * WSZ);
        short* woh = (short*)(wb + 6 * WSZ);  short* wol = (short*)(wb + 7 * WSZ);
        int*      flags = (int*)(wb + 8 * WSZ);
        uint32_t* Mt    = (uint32_t*)(wb + 8 * WSZ + 256);

        build_flags<<<1, 1024, 0, stream>>>((const unsigned char*)maskp, causalp, flags, Mt);

        split_f32<<<(nx4 + 255) / 256, 256, 0, stream>>>(x, xh, xl, nx4, 1.0f);
        dim3 wg((nw4 + 255) / 256, 4);
        split_w4<<<wg, 256, 0, stream>>>(Wq, Wk, Wv, Wo,
                                         wqh, wql, wkh, wkl, wvh, wvl, woh, wol, nw4);

        gemm_bf16s<<<gg, 256, 0, stream>>>(xh, xl, wqh, wql, bq, nullptr, Qhi, Qlo, 0.125f, 2);
        gemm_bf16s<<<gg, 256, 0, stream>>>(xh, xl, wkh, wkl, bk, nullptr, Khi, Klo, 1.0f, 2);
        gemm_bf16s<<<gg, 256, 0, stream>>>(xh, xl, wvh, wvl, bv, Vf, nullptr, nullptr, 1.0f, 1);

        attn_topk<<<BB * NH * (TT / QT), 1024, 0, stream>>>(Qhi, Qlo, Khi, Klo, Vf, Mt, flags,
                                                            Ohi, Olo, nullptr);

        gemm_bf16s<<<gg, 256, 0, stream>>>(Ohi, Olo, woh, wol, bo, out, nullptr, nullptr, 1.0f, 0);
    } else {
        float* Qf  = (float*)(ws);
        float* Kf  = (float*)(ws + TEN);
        float* Vf  = (float*)(ws + 2 * TEN);
        float* O   = (float*)(ws + 3 * TEN);
        short* Qhi = (short*)(ws + 4 * TEN);
        short* Qlo = (short*)(ws + 4 * TEN + HTEN);
        short* Khi = (short*)(ws + 5 * TEN);
        short* Klo = (short*)(ws + 5 * TEN + HTEN);
        int*      flags = (int*)(ws + 6 * TEN);
        uint32_t* Mt    = (uint32_t*)(ws + 6 * TEN + 256);

        build_flags<<<1, 1024, 0, stream>>>((const unsigned char*)maskp, causalp, flags, Mt);
        dim3 g2(DD / 64, (BB * TT) / 64);
        gemm_xwt<<<g2, 256, 0, stream>>>(x, Wq, bq, Qf, BB * TT, DD, DD, 1);
        gemm_xwt<<<g2, 256, 0, stream>>>(x, Wk, bk, Kf, BB * TT, DD, DD, 1);
        gemm_xwt<<<g2, 256, 0, stream>>>(x, Wv, bv, Vf, BB * TT, DD, DD, 1);
        split_f32<<<(nx4 + 255) / 256, 256, 0, stream>>>(Qf, Qhi, Qlo, nx4, 0.125f);
        split_f32<<<(nx4 + 255) / 256, 256, 0, stream>>>(Kf, Khi, Klo, nx4, 1.0f);
        attn_topk<<<BB * NH * (TT / QT), 1024, 0, stream>>>(Qhi, Qlo, Khi, Klo, Vf, Mt, flags,
                                                            nullptr, nullptr, O);
        gemm_xwt<<<g2, 256, 0, stream>>>(O, Wo, bo, out, BB * TT, DD, DD, 0);
    }
}

// Round 8
// 770.446 us; speedup vs baseline: 1.1379x; 1.1379x over previous
//
#include <hip/hip_runtime.h>
#include <hip/hip_bf16.h>
#include <stdint.h>

#define BB 2
#define TT 2048
#define DD 1024
#define NH 16
#define HD 64
#define TOPK 64
#define NEGF (-3.402823466e38f)
#define ORD_NEG 0x00800000u  // ord_u32(NEGF)
#define QT 16                // q-rows per block (1 per wave)
#define KT 256               // keys per tile
#define SELCAP 96

typedef short short8x __attribute__((ext_vector_type(8)));
typedef float floatx4 __attribute__((ext_vector_type(4)));

// ---------- helpers ----------
__device__ __forceinline__ uint32_t ord_u32(float x) {
    uint32_t b = __float_as_uint(x);
    return (b & 0x80000000u) ? ~b : (b | 0x80000000u);
}
__device__ __forceinline__ float unord(uint32_t u) {
    uint32_t b = (u & 0x80000000u) ? (u ^ 0x80000000u) : ~u;
    return __uint_as_float(b);
}
__device__ __forceinline__ short bf16_rne(float x) {
    uint32_t u = __float_as_uint(x);
    u += 0x7FFFu + ((u >> 16) & 1u);
    return (short)(u >> 16);
}
__device__ __forceinline__ float bf16_to_f(short h) {
    return __uint_as_float(((uint32_t)(uint16_t)h) << 16);
}
__device__ __forceinline__ bool mask_at(const void* m, int mode, int idx) {
    if (mode == 0) return ((const int*)m)[idx] != 0;
    if (mode == 1) return ((const unsigned char*)m)[idx] != 0;
    return ((const float*)m)[idx] != 0.0f;
}

// ---------- DPP wave-64 reductions ----------
__device__ __forceinline__ int dpp_wsum(int v) {
    v += __builtin_amdgcn_update_dpp(0, v, 0x111, 0xf, 0xf, true);
    v += __builtin_amdgcn_update_dpp(0, v, 0x112, 0xf, 0xf, true);
    v += __builtin_amdgcn_update_dpp(0, v, 0x114, 0xf, 0xf, true);
    v += __builtin_amdgcn_update_dpp(0, v, 0x118, 0xf, 0xf, true);
    v += __builtin_amdgcn_update_dpp(0, v, 0x142, 0xa, 0xf, true);
    v += __builtin_amdgcn_update_dpp(0, v, 0x143, 0xc, 0xf, true);
    return __builtin_amdgcn_readlane(v, 63);
}
__device__ __forceinline__ uint32_t dpp_wumax(uint32_t v) {
    uint32_t t;
    t = (uint32_t)__builtin_amdgcn_update_dpp(0, (int)v, 0x111, 0xf, 0xf, true); v = v > t ? v : t;
    t = (uint32_t)__builtin_amdgcn_update_dpp(0, (int)v, 0x112, 0xf, 0xf, true); v = v > t ? v : t;
    t = (uint32_t)__builtin_amdgcn_update_dpp(0, (int)v, 0x114, 0xf, 0xf, true); v = v > t ? v : t;
    t = (uint32_t)__builtin_amdgcn_update_dpp(0, (int)v, 0x118, 0xf, 0xf, true); v = v > t ? v : t;
    t = (uint32_t)__builtin_amdgcn_update_dpp(0, (int)v, 0x142, 0xa, 0xf, true); v = v > t ? v : t;
    t = (uint32_t)__builtin_amdgcn_update_dpp(0, (int)v, 0x143, 0xc, 0xf, true); v = v > t ? v : t;
    return (uint32_t)__builtin_amdgcn_readlane((int)v, 63);
}
__device__ __forceinline__ float dpp_fsum(float v) {
    v += __uint_as_float((uint32_t)__builtin_amdgcn_update_dpp(0, (int)__float_as_uint(v), 0x111, 0xf, 0xf, true));
    v += __uint_as_float((uint32_t)__builtin_amdgcn_update_dpp(0, (int)__float_as_uint(v), 0x112, 0xf, 0xf, true));
    v += __uint_as_float((uint32_t)__builtin_amdgcn_update_dpp(0, (int)__float_as_uint(v), 0x114, 0xf, 0xf, true));
    v += __uint_as_float((uint32_t)__builtin_amdgcn_update_dpp(0, (int)__float_as_uint(v), 0x118, 0xf, 0xf, true));
    v += __uint_as_float((uint32_t)__builtin_amdgcn_update_dpp(0, (int)__float_as_uint(v), 0x142, 0xa, 0xf, true));
    v += __uint_as_float((uint32_t)__builtin_amdgcn_update_dpp(0, (int)__float_as_uint(v), 0x143, 0xc, 0xf, true));
    return __uint_as_float((uint32_t)__builtin_amdgcn_readlane((int)__float_as_uint(v), 63));
}

// ---------- mask detection + transposed bitmask build ----------
__global__ void __launch_bounds__(1024) build_flags(
    const unsigned char* raw, const int* causalp, int* flags, uint32_t* Mt)
{
    __shared__ int odd_nz, big, s_mode;
    __shared__ uint32_t smt[BB * 64];
    const int tid = threadIdx.x;
    if (tid == 0) { odd_nz = 0; big = 0; }
    if (tid < BB * 64) smt[tid] = 0;
    __syncthreads();
    for (int i = tid; i < BB * TT; i += 1024) {
        unsigned char c = raw[i];
        if ((i & 3) && c) atomicOr(&odd_nz, 1);
        if (c > 1) atomicOr(&big, 1);
    }
    __syncthreads();
    if (tid == 0) {
        int mode = odd_nz ? (big ? 2 : 1) : 0;
        s_mode = mode;
        flags[0] = mode;
        flags[1] = (causalp[0] != 0) ? 1 : 0;
    }
    __syncthreads();
    const int mode = s_mode;
    const int w = tid >> 3, g = tid & 7;
    const int bb = w >> 6, l = w & 63;
    uint32_t bits = 0;
#pragma unroll
    for (int si = 0; si < 4; ++si) {
        int s = g * 4 + si;
        if (mask_at(raw, mode, bb * TT + l + 64 * s)) bits |= (1u << s);
    }
    if (bits) atomicOr(&smt[w], bits);
    __syncthreads();
    if (tid < BB * 64) Mt[tid] = smt[tid];
}

// ---------- f32 -> (hi, lo) bf16 split (with scale) ----------
__global__ void __launch_bounds__(256) split_f32(
    const float* __restrict__ in, short* __restrict__ hi, short* __restrict__ lo,
    int n4, float scale)
{
    int i = blockIdx.x * blockDim.x + threadIdx.x;
    if (i >= n4) return;
    float4 v = ((const float4*)in)[i];
    float f[4] = {v.x * scale, v.y * scale, v.z * scale, v.w * scale};
    short hh[4], ll[4];
#pragma unroll
    for (int j = 0; j < 4; ++j) {
        hh[j] = bf16_rne(f[j]);
        ll[j] = bf16_rne(f[j] - bf16_to_f(hh[j]));
    }
    short4 h4; h4.x = hh[0]; h4.y = hh[1]; h4.z = hh[2]; h4.w = hh[3];
    short4 l4; l4.x = ll[0]; l4.y = ll[1]; l4.z = ll[2]; l4.w = ll[3];
    ((short4*)hi)[i] = h4;
    ((short4*)lo)[i] = l4;
}

// ---------- 4 weights split in one launch ----------
__global__ void __launch_bounds__(256) split_w4(
    const float* __restrict__ W0, const float* __restrict__ W1,
    const float* __restrict__ W2, const float* __restrict__ W3,
    short* __restrict__ h0, short* __restrict__ l0, short* __restrict__ h1, short* __restrict__ l1,
    short* __restrict__ h2, short* __restrict__ l2, short* __restrict__ h3, short* __restrict__ l3,
    int n4)
{
    int i = blockIdx.x * blockDim.x + threadIdx.x;
    if (i >= n4) return;
    const int w = blockIdx.y;
    const float* in = (w == 0) ? W0 : (w == 1) ? W1 : (w == 2) ? W2 : W3;
    short* hi = (w == 0) ? h0 : (w == 1) ? h1 : (w == 2) ? h2 : h3;
    short* lo = (w == 0) ? l0 : (w == 1) ? l1 : (w == 2) ? l2 : l3;
    float4 v = ((const float4*)in)[i];
    float f[4] = {v.x, v.y, v.z, v.w};
    short hh[4], ll[4];
#pragma unroll
    for (int j = 0; j < 4; ++j) {
        hh[j] = bf16_rne(f[j]);
        ll[j] = bf16_rne(f[j] - bf16_to_f(hh[j]));
    }
    short4 h4; h4.x = hh[0]; h4.y = hh[1]; h4.z = hh[2]; h4.w = hh[3];
    short4 l4; l4.x = ll[0]; l4.y = ll[1]; l4.z = ll[2]; l4.w = ll[3];
    ((short4*)hi)[i] = h4;
    ((short4*)lo)[i] = l4;
}

// ---------- split-bf16 MFMA GEMM, 128x64 tile, XCD-panel swizzle, dbuf ----------
// 1D grid of 512 blocks. Each XCD (bid&7) owns 4 consecutive 128-row A-panels
// and runs all 16 N-blocks of a panel back-to-back -> A-panel L2-resident.
// mode 0: f32 row-major; mode 1: f32 split-heads; mode 2: bf16 hi/lo split-heads (scaled)
__global__ void __launch_bounds__(256) gemm_bf16s(
    const short* __restrict__ Ah, const short* __restrict__ Al,
    const short* __restrict__ Bh, const short* __restrict__ Bl,
    const float* __restrict__ bias, float* __restrict__ Cf,
    short* __restrict__ Ch, short* __restrict__ Cl, float scale, int mode)
{
    const int bid = blockIdx.x;               // 0..511
    const int xcd = bid & 7, slot = bid >> 3; // slot 0..63
    const int panel = xcd * 4 + (slot >> 4);  // 4 panels per XCD
    const int ncol  = slot & 15;
    const int tid = threadIdx.x, lane = tid & 63, wv = tid >> 6;
    const int wr = wv >> 1, wc = wv & 1;
    const int m0 = panel * 128 + wr * 64;
    const int n0 = ncol * 64 + wc * 32;
    const int lrow = lane & 15, lk = (lane >> 4) * 8;

    floatx4 acc[4][2];
#pragma unroll
    for (int i = 0; i < 4; ++i)
#pragma unroll
        for (int j = 0; j < 2; ++j) acc[i][j] = (floatx4){0.f, 0.f, 0.f, 0.f};

    auto ldfr = [&](int kk, short8x* pah, short8x* pal, short8x* pbh, short8x* pbl) {
#pragma unroll
        for (int mb = 0; mb < 4; ++mb) {
            size_t off = (size_t)(m0 + mb * 16 + lrow) * DD + kk + lk;
            pah[mb] = *(const short8x*)(Ah + off);
            pal[mb] = *(const short8x*)(Al + off);
        }
#pragma unroll
        for (int nb = 0; nb < 2; ++nb) {
            size_t off = (size_t)(n0 + nb * 16 + lrow) * DD + kk + lk;
            pbh[nb] = *(const short8x*)(Bh + off);
            pbl[nb] = *(const short8x*)(Bl + off);
        }
    };
    auto domfma = [&](short8x* pah, short8x* pal, short8x* pbh, short8x* pbl) {
#pragma unroll
        for (int mb = 0; mb < 4; ++mb)
#pragma unroll
            for (int nb = 0; nb < 2; ++nb) {
                acc[mb][nb] = __builtin_amdgcn_mfma_f32_16x16x32_bf16(pah[mb], pbh[nb], acc[mb][nb], 0, 0, 0);
                acc[mb][nb] = __builtin_amdgcn_mfma_f32_16x16x32_bf16(pah[mb], pbl[nb], acc[mb][nb], 0, 0, 0);
                acc[mb][nb] = __builtin_amdgcn_mfma_f32_16x16x32_bf16(pal[mb], pbh[nb], acc[mb][nb], 0, 0, 0);
            }
    };

    short8x A0[4], L0[4], B0[2], C0[2];
    short8x A1[4], L1[4], B1[2], C1[2];
    ldfr(0, A0, L0, B0, C0);
    for (int kk = 0; kk < DD; kk += 64) {
        ldfr(kk + 32, A1, L1, B1, C1);
        domfma(A0, L0, B0, C0);
        if (kk + 64 < DD) ldfr(kk + 64, A0, L0, B0, C0);
        domfma(A1, L1, B1, C1);
    }

#pragma unroll
    for (int mb = 0; mb < 4; ++mb)
#pragma unroll
        for (int nb = 0; nb < 2; ++nb) {
            int n = n0 + nb * 16 + lrow;
            float bv = bias[n];
#pragma unroll
            for (int j = 0; j < 4; ++j) {
                int m = m0 + mb * 16 + (lane >> 4) * 4 + j;
                float v = acc[mb][nb][j] + bv;
                if (mode == 0) {
                    Cf[(size_t)m * DD + n] = v;
                } else {
                    int b = m >> 11, t = m & (TT - 1), h = n >> 6, dh = n & (HD - 1);
                    size_t idx = (((size_t)b * NH + h) * TT + t) * HD + dh;
                    if (mode == 1) {
                        Cf[idx] = v;
                    } else {
                        v *= scale;
                        short hi16 = bf16_rne(v);
                        Ch[idx] = hi16;
                        Cl[idx] = bf16_rne(v - bf16_to_f(hi16));
                    }
                }
            }
        }
}

// ---------- f32 GEMM (fallback) ----------
__global__ void __launch_bounds__(256) gemm_xwt(
    const float* __restrict__ A, const float* __restrict__ W,
    const float* __restrict__ bias, float* __restrict__ C,
    int M, int N, int K, int split_heads)
{
    __shared__ float As[64][17];
    __shared__ float Ws[64][17];
    const int tid = threadIdx.x;
    const int tx = tid & 15, ty = tid >> 4;
    const int arow = blockIdx.y * 64, bcol = blockIdx.x * 64;
    float acc[4][4] = {};

    for (int k0 = 0; k0 < K; k0 += 16) {
        const int r = tid >> 2, c = (tid & 3) * 4;
        float4 a4 = *(const float4*)(A + (size_t)(arow + r) * K + k0 + c);
        As[r][c] = a4.x; As[r][c + 1] = a4.y; As[r][c + 2] = a4.z; As[r][c + 3] = a4.w;
        float4 w4 = *(const float4*)(W + (size_t)(bcol + r) * K + k0 + c);
        Ws[r][c] = w4.x; Ws[r][c + 1] = w4.y; Ws[r][c + 2] = w4.z; Ws[r][c + 3] = w4.w;
        __syncthreads();
#pragma unroll
        for (int k = 0; k < 16; ++k) {
            float a0 = As[ty * 4 + 0][k], a1 = As[ty * 4 + 1][k];
            float a2 = As[ty * 4 + 2][k], a3 = As[ty * 4 + 3][k];
            float w0 = Ws[tx * 4 + 0][k], w1 = Ws[tx * 4 + 1][k];
            float w2 = Ws[tx * 4 + 2][k], w3 = Ws[tx * 4 + 3][k];
            acc[0][0] += a0 * w0; acc[0][1] += a0 * w1; acc[0][2] += a0 * w2; acc[0][3] += a0 * w3;
            acc[1][0] += a1 * w0; acc[1][1] += a1 * w1; acc[1][2] += a1 * w2; acc[1][3] += a1 * w3;
            acc[2][0] += a2 * w0; acc[2][1] += a2 * w1; acc[2][2] += a2 * w2; acc[2][3] += a2 * w3;
            acc[3][0] += a3 * w0; acc[3][1] += a3 * w1; acc[3][2] += a3 * w2; acc[3][3] += a3 * w3;
        }
        __syncthreads();
    }

#pragma unroll
    for (int i = 0; i < 4; ++i) {
        int m = arow + ty * 4 + i;
#pragma unroll
        for (int j = 0; j < 4; ++j) {
            int n = bcol + tx * 4 + j;
            float v = acc[i][j] + bias[n];
            if (split_heads) {
                int b = m / TT, t = m % TT, h = n / HD, dh = n % HD;
                C[(((size_t)b * NH + h) * TT + t) * HD + dh] = v;
            } else {
                C[(size_t)m * N + n] = v;
            }
        }
    }
}

// ---------- MFMA attention with exact register-resident top-64 ----------
// XCD-swizzled 1D grid: each XCD owns 4 heads -> K/V stay L2-resident.
__global__ void __launch_bounds__(1024) attn_topk(
    const short* __restrict__ Qhi, const short* __restrict__ Qlo,
    const short* __restrict__ Khi, const short* __restrict__ Klo,
    const float* __restrict__ V, const uint32_t* __restrict__ Mt,
    const int* __restrict__ flags, short* __restrict__ Ohi,
    short* __restrict__ Olo, float* __restrict__ Of)
{
    __shared__ float s_S[2][QT][KT + 1];     // 32.9 KB (double-buffered)
    __shared__ int2  s_sel[QT][SELCAP];      // packed (key<<6, w bits)

    const int tid = threadIdx.x, lane = tid & 63, wv = tid >> 6;
    const int d = blockIdx.x;                // 0..4095, XCD = d & 7
    const int xcd = d & 7, chunk = d >> 3;
    const int bh = (xcd << 2) | (chunk >> 7);  // 4 heads per XCD
    const int qt = chunk & 127;
    const int b = bh >> 4, h = bh & 15;
    const int causal = flags[1];
    const size_t hb = (size_t)bh * (size_t)TT * HD;
    const int r0 = qt * QT;
    const int gq = r0 + wv;
    const float* __restrict__ Vh = V + hb;
    const float* __restrict__ Vl = Vh + lane;

    short8x qhi[2], qlo[2];
    {
        const size_t qoff = hb + (size_t)(r0 + (lane & 15)) * HD + (lane >> 4) * 8;
        qhi[0] = *(const short8x*)(Qhi + qoff);
        qhi[1] = *(const short8x*)(Qhi + qoff + 32);
        qlo[0] = *(const short8x*)(Qlo + qoff);
        qlo[1] = *(const short8x*)(Qlo + qoff + 32);
    }

    const uint32_t mwords = Mt[b * 64 + lane];

    uint32_t lgo[32];
#pragma unroll
    for (int i = 0; i < 32; ++i) lgo[i] = ORD_NEG;

    const int lastT = causal ? ((r0 + QT - 1) >> 8) : 7;

#pragma unroll
    for (int t = 0; t < 8; ++t) {
        if (t <= lastT) {
            const size_t koff = hb + (size_t)(t * KT + wv * 16 + (lane & 15)) * HD + (lane >> 4) * 8;
            short8x kh0 = *(const short8x*)(Khi + koff);
            short8x kh1 = *(const short8x*)(Khi + koff + 32);
            short8x kl0 = *(const short8x*)(Klo + koff);
            short8x kl1 = *(const short8x*)(Klo + koff + 32);
            floatx4 acc = {0.f, 0.f, 0.f, 0.f};
            acc = __builtin_amdgcn_mfma_f32_16x16x32_bf16(qhi[0], kh0, acc, 0, 0, 0);
            acc = __builtin_amdgcn_mfma_f32_16x16x32_bf16(qhi[0], kl0, acc, 0, 0, 0);
            acc = __builtin_amdgcn_mfma_f32_16x16x32_bf16(qlo[0], kh0, acc, 0, 0, 0);
            acc = __builtin_amdgcn_mfma_f32_16x16x32_bf16(qhi[1], kh1, acc, 0, 0, 0);
            acc = __builtin_amdgcn_mfma_f32_16x16x32_bf16(qhi[1], kl1, acc, 0, 0, 0);
            acc = __builtin_amdgcn_mfma_f32_16x16x32_bf16(qlo[1], kh1, acc, 0, 0, 0);
#pragma unroll
            for (int j = 0; j < 4; ++j)
                s_S[t & 1][(lane >> 4) * 4 + j][wv * 16 + (lane & 15)] = acc[j];
            __syncthreads();
#pragma unroll
            for (int j = 0; j < 4; ++j) {
                float sv = s_S[t & 1][wv][j * 64 + lane];
                int key = t * KT + j * 64 + lane;
                bool blocked = ((mwords >> (t * 4 + j)) & 1u) || (causal && key > gq);
                lgo[t * 4 + j] = blocked ? ORD_NEG : ord_u32(sv);
            }
        }
    }

    // ---- epilogue: exact top-64 select + softmax + sparse A*V ----
    uint32_t moL = 0;
#pragma unroll
    for (int i = 0; i < 32; ++i) {
        uint32_t u = lgo[i];
        moL = u > moL ? u : moL;
    }
    const uint32_t mo = dpp_wumax(moL);

    auto wcount = [&](uint32_t thrv) -> int {
        int c = 0;
#pragma unroll
        for (int i = 0; i < 32; ++i) c += (lgo[i] >= thrv) ? 1 : 0;
        return dpp_wsum(c);
    };

    float outv;
    if (mo == ORD_NEG) {
        // fully blocked row: reference softmax is uniform over ALL keys
        float a0 = 0.f, a1 = 0.f, a2 = 0.f, a3 = 0.f;
        for (int j = 0; j < TT; j += 4) {
            a0 += Vh[(j + 0) * HD + lane];
            a1 += Vh[(j + 1) * HD + lane];
            a2 += Vh[(j + 2) * HD + lane];
            a3 += Vh[(j + 3) * HD + lane];
        }
        outv = (a0 + a1 + a2 + a3) * (1.0f / TT);
    } else {
        const float mF = unord(mo);
        uint32_t thr = 0; uint32_t lo_b = 0, hi_b = 0; int done = 0;
        {
            uint32_t p1 = ord_u32(mF - 2.0f);
            int c1 = wcount(p1);
            if (c1 == TOPK) { thr = p1; done = 1; }
            else if (c1 > TOPK) { lo_b = p1; hi_b = mo; }
            else {
                uint32_t p2 = ord_u32(mF - 4.0f);
                int c2 = wcount(p2);
                if (c2 == TOPK) { thr = p2; done = 1; }
                else if (c2 > TOPK) { lo_b = p2; hi_b = p1; }
                else {
                    uint32_t p3 = ord_u32(mF - 15.0f);
                    int c3 = wcount(p3);
                    if (c3 <= TOPK) { thr = p3; done = 1; }  // <64 candidates: rest < e^-15
                    else { lo_b = p3; hi_b = p2; }
                }
            }
        }
        if (!done) {
            while (hi_b - lo_b > 1u) {
                uint32_t mid = lo_b + ((hi_b - lo_b) >> 1);
                int c = wcount(mid);
                if (c == TOPK) { lo_b = mid; break; }
                if (c > TOPK) lo_b = mid; else hi_b = mid;
            }
            thr = lo_b;
        }

        float Sp = 0.f;
#pragma unroll
        for (int i = 0; i < 32; ++i) {
            uint32_t u = lgo[i];
            float w = 0.f;
            if (u >= thr) w = __expf(unord(u) - mF);
            Sp += w;
            lgo[i] = (w > 0.f) ? __float_as_uint(w) : 0u;
        }
        const float S = dpp_fsum(Sp);

        // ballot/mbcnt compaction (no scan, no atomics)
        int base = 0;
#pragma unroll
        for (int i = 0; i < 32; ++i) {
            uint32_t wbits = lgo[i];
            unsigned long long msk = __ballot(wbits != 0);
            if (wbits) {
                int below = __builtin_amdgcn_mbcnt_hi((uint32_t)(msk >> 32),
                            __builtin_amdgcn_mbcnt_lo((uint32_t)msk, 0));
                int pos = base + below;
                if (pos < SELCAP) {
                    int keyoff = (((i >> 2) * KT + (i & 3) * 64 + lane) << 6);
                    s_sel[wv][pos] = make_int2(keyoff, (int)wbits);
                }
            }
            base += (int)__popcll(msk);
        }
        int cnt = base < SELCAP ? base : SELCAP;

        // sparse A*V: scalar (readfirstlane) key base -> coalesced V row reads
        float acc = 0.f;
        int i2 = 0;
        for (; i2 + 4 <= cnt; i2 += 4) {
            int2 e0 = s_sel[wv][i2],     e1 = s_sel[wv][i2 + 1];
            int2 e2 = s_sel[wv][i2 + 2], e3 = s_sel[wv][i2 + 3];
            int k0 = __builtin_amdgcn_readfirstlane(e0.x);
            int k1 = __builtin_amdgcn_readfirstlane(e1.x);
            int k2 = __builtin_amdgcn_readfirstlane(e2.x);
            int k3 = __builtin_amdgcn_readfirstlane(e3.x);
            float w0 = __uint_as_float((uint32_t)__builtin_amdgcn_readfirstlane(e0.y));
            float w1 = __uint_as_float((uint32_t)__builtin_amdgcn_readfirstlane(e1.y));
            float w2 = __uint_as_float((uint32_t)__builtin_amdgcn_readfirstlane(e2.y));
            float w3 = __uint_as_float((uint32_t)__builtin_amdgcn_readfirstlane(e3.y));
            acc += w0 * Vl[k0];
            acc += w1 * Vl[k1];
            acc += w2 * Vl[k2];
            acc += w3 * Vl[k3];
        }
        for (; i2 < cnt; ++i2) {
            int2 e = s_sel[wv][i2];
            int k = __builtin_amdgcn_readfirstlane(e.x);
            float w = __uint_as_float((uint32_t)__builtin_amdgcn_readfirstlane(e.y));
            acc += w * Vl[k];
        }
        outv = acc / S;
    }
    const size_t oidx = ((size_t)b * TT + gq) * DD + h * HD + lane;
    if (Of) {
        Of[oidx] = outv;
    } else {
        short hi16 = bf16_rne(outv);
        Ohi[oidx] = hi16;
        Olo[oidx] = bf16_rne(outv - bf16_to_f(hi16));
    }
}

// ---------- launch ----------
extern "C" void kernel_launch(void* const* d_in, const int* in_sizes, int n_in,
                              void* d_out, int out_size, void* d_ws, size_t ws_size,
                              hipStream_t stream) {
    const float* x  = (const float*)d_in[0];
    const float* Wq = (const float*)d_in[1];
    const float* bq = (const float*)d_in[2];
    const float* Wk = (const float*)d_in[3];
    const float* bk = (const float*)d_in[4];
    const float* Wv = (const float*)d_in[5];
    const float* bv = (const float*)d_in[6];
    const float* Wo = (const float*)d_in[7];
    const float* bo = (const float*)d_in[8];
    const void*  maskp = d_in[9];
    const int*   causalp = (const int*)d_in[10];
    float* out = (float*)d_out;

    char* ws = (char*)d_ws;
    const size_t TEN  = (size_t)BB * TT * DD * sizeof(float);  // 16.78 MB
    const size_t HTEN = TEN / 2;
    const size_t WSZ  = (size_t)DD * DD * 2;                   // 2 MB bf16 weight
    const size_t NEED = 6 * TEN + 4096;

    const int nx4 = BB * TT * DD / 4, nw4 = DD * DD / 4;

    if (ws_size >= NEED) {
        float* Vf   = (float*)(ws);
        short* xh   = (short*)(ws + TEN);
        short* xl   = (short*)(ws + TEN + HTEN);
        short* Qhi  = (short*)(ws + 2 * TEN);
        short* Qlo  = (short*)(ws + 2 * TEN + HTEN);
        short* Khi  = (short*)(ws + 3 * TEN);
        short* Klo  = (short*)(ws + 3 * TEN + HTEN);
        short* Ohi  = (short*)(ws + 4 * TEN);
        short* Olo  = (short*)(ws + 4 * TEN + HTEN);
        char*  wb   = ws + 5 * TEN;
        short* wqh = (short*)(wb);            short* wql = (short*)(wb + WSZ);
        short* wkh = (short*)(wb + 2 * WSZ);  short* wkl = (short*)(wb + 3 * WSZ);
        short* wvh = (short*)(wb + 4 * WSZ);  short* wvl = (short*)(wb + 5 * WSZ);
        short* woh = (short*)(wb + 6 * WSZ);  short* wol = (short*)(wb + 7 * WSZ);
        int*      flags = (int*)(wb + 8 * WSZ);
        uint32_t* Mt    = (uint32_t*)(wb + 8 * WSZ + 256);

        build_flags<<<1, 1024, 0, stream>>>((const unsigned char*)maskp, causalp, flags, Mt);

        split_f32<<<(nx4 + 255) / 256, 256, 0, stream>>>(x, xh, xl, nx4, 1.0f);
        dim3 wg((nw4 + 255) / 256, 4);
        split_w4<<<wg, 256, 0, stream>>>(Wq, Wk, Wv, Wo,
                                         wqh, wql, wkh, wkl, wvh, wvl, woh, wol, nw4);

        gemm_bf16s<<<512, 256, 0, stream>>>(xh, xl, wqh, wql, bq, nullptr, Qhi, Qlo, 0.125f, 2);
        gemm_bf16s<<<512, 256, 0, stream>>>(xh, xl, wkh, wkl, bk, nullptr, Khi, Klo, 1.0f, 2);
        gemm_bf16s<<<512, 256, 0, stream>>>(xh, xl, wvh, wvl, bv, Vf, nullptr, nullptr, 1.0f, 1);

        attn_topk<<<BB * NH * (TT / QT), 1024, 0, stream>>>(Qhi, Qlo, Khi, Klo, Vf, Mt, flags,
                                                            Ohi, Olo, nullptr);

        gemm_bf16s<<<512, 256, 0, stream>>>(Ohi, Olo, woh, wol, bo, out, nullptr, nullptr, 1.0f, 0);
    } else {
        float* Qf  = (float*)(ws);
        float* Kf  = (float*)(ws + TEN);
        float* Vf  = (float*)(ws + 2 * TEN);
        float* O   = (float*)(ws + 3 * TEN);
        short* Qhi = (short*)(ws + 4 * TEN);
        short* Qlo = (short*)(ws + 4 * TEN + HTEN);
        short* Khi = (short*)(ws + 5 * TEN);
        short* Klo = (short*)(ws + 5 * TEN + HTEN);
        int*      flags = (int*)(ws + 6 * TEN);
        uint32_t* Mt    = (uint32_t*)(ws + 6 * TEN + 256);

        build_flags<<<1, 1024, 0, stream>>>((const unsigned char*)maskp, causalp, flags, Mt);
        dim3 g2(DD / 64, (BB * TT) / 64);
        gemm_xwt<<<g2, 256, 0, stream>>>(x, Wq, bq, Qf, BB * TT, DD, DD, 1);
        gemm_xwt<<<g2, 256, 0, stream>>>(x, Wk, bk, Kf, BB * TT, DD, DD, 1);
        gemm_xwt<<<g2, 256, 0, stream>>>(x, Wv, bv, Vf, BB * TT, DD, DD, 1);
        split_f32<<<(nx4 + 255) / 256, 256, 0, stream>>>(Qf, Qhi, Qlo, nx4, 0.125f);
        split_f32<<<(nx4 + 255) / 256, 256, 0, stream>>>(Kf, Khi, Klo, nx4, 1.0f);
        attn_topk<<<BB * NH * (TT / QT), 1024, 0, stream>>>(Qhi, Qlo, Khi, Klo, Vf, Mt, flags,
                                                            nullptr, nullptr, O);
        gemm_xwt<<<g2, 256, 0, stream>>>(O, Wo, bo, out, BB * TT, DD, DD, 0);
    }
}

// Round 9
// 757.083 us; speedup vs baseline: 1.1580x; 1.0177x over previous
//
#include <hip/hip_runtime.h>
#include <hip/hip_bf16.h>
#include <stdint.h>

#define BB 2
#define TT 2048
#define DD 1024
#define NH 16
#define HD 64
#define TOPK 64
#define NEGF (-3.402823466e38f)
#define ORD_NEG 0x00800000u  // ord_u32(NEGF)
#define QT 16                // q-rows per block (1 per wave)
#define KT 256               // keys per tile

typedef short short8x __attribute__((ext_vector_type(8)));
typedef float floatx4 __attribute__((ext_vector_type(4)));

// ---------- helpers ----------
__device__ __forceinline__ uint32_t ord_u32(float x) {
    uint32_t b = __float_as_uint(x);
    return (b & 0x80000000u) ? ~b : (b | 0x80000000u);
}
__device__ __forceinline__ float unord(uint32_t u) {
    uint32_t b = (u & 0x80000000u) ? (u ^ 0x80000000u) : ~u;
    return __uint_as_float(b);
}
__device__ __forceinline__ short bf16_rne(float x) {
    uint32_t u = __float_as_uint(x);
    u += 0x7FFFu + ((u >> 16) & 1u);
    return (short)(u >> 16);
}
__device__ __forceinline__ float bf16_to_f(short h) {
    return __uint_as_float(((uint32_t)(uint16_t)h) << 16);
}
__device__ __forceinline__ bool mask_at(const void* m, int mode, int idx) {
    if (mode == 0) return ((const int*)m)[idx] != 0;
    if (mode == 1) return ((const unsigned char*)m)[idx] != 0;
    return ((const float*)m)[idx] != 0.0f;
}

// ---------- DPP wave-64 reductions ----------
__device__ __forceinline__ int dpp_wsum(int v) {
    v += __builtin_amdgcn_update_dpp(0, v, 0x111, 0xf, 0xf, true);
    v += __builtin_amdgcn_update_dpp(0, v, 0x112, 0xf, 0xf, true);
    v += __builtin_amdgcn_update_dpp(0, v, 0x114, 0xf, 0xf, true);
    v += __builtin_amdgcn_update_dpp(0, v, 0x118, 0xf, 0xf, true);
    v += __builtin_amdgcn_update_dpp(0, v, 0x142, 0xa, 0xf, true);
    v += __builtin_amdgcn_update_dpp(0, v, 0x143, 0xc, 0xf, true);
    return __builtin_amdgcn_readlane(v, 63);
}
__device__ __forceinline__ uint32_t dpp_wumax(uint32_t v) {
    uint32_t t;
    t = (uint32_t)__builtin_amdgcn_update_dpp(0, (int)v, 0x111, 0xf, 0xf, true); v = v > t ? v : t;
    t = (uint32_t)__builtin_amdgcn_update_dpp(0, (int)v, 0x112, 0xf, 0xf, true); v = v > t ? v : t;
    t = (uint32_t)__builtin_amdgcn_update_dpp(0, (int)v, 0x114, 0xf, 0xf, true); v = v > t ? v : t;
    t = (uint32_t)__builtin_amdgcn_update_dpp(0, (int)v, 0x118, 0xf, 0xf, true); v = v > t ? v : t;
    t = (uint32_t)__builtin_amdgcn_update_dpp(0, (int)v, 0x142, 0xa, 0xf, true); v = v > t ? v : t;
    t = (uint32_t)__builtin_amdgcn_update_dpp(0, (int)v, 0x143, 0xc, 0xf, true); v = v > t ? v : t;
    return (uint32_t)__builtin_amdgcn_readlane((int)v, 63);
}
__device__ __forceinline__ float dpp_fsum(float v) {
    v += __uint_as_float((uint32_t)__builtin_amdgcn_update_dpp(0, (int)__float_as_uint(v), 0x111, 0xf, 0xf, true));
    v += __uint_as_float((uint32_t)__builtin_amdgcn_update_dpp(0, (int)__float_as_uint(v), 0x112, 0xf, 0xf, true));
    v += __uint_as_float((uint32_t)__builtin_amdgcn_update_dpp(0, (int)__float_as_uint(v), 0x114, 0xf, 0xf, true));
    v += __uint_as_float((uint32_t)__builtin_amdgcn_update_dpp(0, (int)__float_as_uint(v), 0x118, 0xf, 0xf, true));
    v += __uint_as_float((uint32_t)__builtin_amdgcn_update_dpp(0, (int)__float_as_uint(v), 0x142, 0xa, 0xf, true));
    v += __uint_as_float((uint32_t)__builtin_amdgcn_update_dpp(0, (int)__float_as_uint(v), 0x143, 0xc, 0xf, true));
    return __uint_as_float((uint32_t)__builtin_amdgcn_readlane((int)__float_as_uint(v), 63));
}

// ---------- mask detection + transposed bitmask build ----------
__global__ void __launch_bounds__(1024) build_flags(
    const unsigned char* raw, const int* causalp, int* flags, uint32_t* Mt)
{
    __shared__ int odd_nz, big, s_mode;
    __shared__ uint32_t smt[BB * 64];
    const int tid = threadIdx.x;
    if (tid == 0) { odd_nz = 0; big = 0; }
    if (tid < BB * 64) smt[tid] = 0;
    __syncthreads();
    for (int i = tid; i < BB * TT; i += 1024) {
        unsigned char c = raw[i];
        if ((i & 3) && c) atomicOr(&odd_nz, 1);
        if (c > 1) atomicOr(&big, 1);
    }
    __syncthreads();
    if (tid == 0) {
        int mode = odd_nz ? (big ? 2 : 1) : 0;
        s_mode = mode;
        flags[0] = mode;
        flags[1] = (causalp[0] != 0) ? 1 : 0;
    }
    __syncthreads();
    const int mode = s_mode;
    const int w = tid >> 3, g = tid & 7;
    const int bb = w >> 6, l = w & 63;
    uint32_t bits = 0;
#pragma unroll
    for (int si = 0; si < 4; ++si) {
        int s = g * 4 + si;
        if (mask_at(raw, mode, bb * TT + l + 64 * s)) bits |= (1u << s);
    }
    if (bits) atomicOr(&smt[w], bits);
    __syncthreads();
    if (tid < BB * 64) Mt[tid] = smt[tid];
}

// ---------- f32 -> (hi, lo) bf16 split (with scale) ----------
__global__ void __launch_bounds__(256) split_f32(
    const float* __restrict__ in, short* __restrict__ hi, short* __restrict__ lo,
    int n4, float scale)
{
    int i = blockIdx.x * blockDim.x + threadIdx.x;
    if (i >= n4) return;
    float4 v = ((const float4*)in)[i];
    float f[4] = {v.x * scale, v.y * scale, v.z * scale, v.w * scale};
    short hh[4], ll[4];
#pragma unroll
    for (int j = 0; j < 4; ++j) {
        hh[j] = bf16_rne(f[j]);
        ll[j] = bf16_rne(f[j] - bf16_to_f(hh[j]));
    }
    short4 h4; h4.x = hh[0]; h4.y = hh[1]; h4.z = hh[2]; h4.w = hh[3];
    short4 l4; l4.x = ll[0]; l4.y = ll[1]; l4.z = ll[2]; l4.w = ll[3];
    ((short4*)hi)[i] = h4;
    ((short4*)lo)[i] = l4;
}

// ---------- 4 weights split in one launch ----------
__global__ void __launch_bounds__(256) split_w4(
    const float* __restrict__ W0, const float* __restrict__ W1,
    const float* __restrict__ W2, const float* __restrict__ W3,
    short* __restrict__ h0, short* __restrict__ l0, short* __restrict__ h1, short* __restrict__ l1,
    short* __restrict__ h2, short* __restrict__ l2, short* __restrict__ h3, short* __restrict__ l3,
    int n4)
{
    int i = blockIdx.x * blockDim.x + threadIdx.x;
    if (i >= n4) return;
    const int w = blockIdx.y;
    const float* in = (w == 0) ? W0 : (w == 1) ? W1 : (w == 2) ? W2 : W3;
    short* hi = (w == 0) ? h0 : (w == 1) ? h1 : (w == 2) ? h2 : h3;
    short* lo = (w == 0) ? l0 : (w == 1) ? l1 : (w == 2) ? l2 : l3;
    float4 v = ((const float4*)in)[i];
    float f[4] = {v.x, v.y, v.z, v.w};
    short hh[4], ll[4];
#pragma unroll
    for (int j = 0; j < 4; ++j) {
        hh[j] = bf16_rne(f[j]);
        ll[j] = bf16_rne(f[j] - bf16_to_f(hh[j]));
    }
    short4 h4; h4.x = hh[0]; h4.y = hh[1]; h4.z = hh[2]; h4.w = hh[3];
    short4 l4; l4.x = ll[0]; l4.y = ll[1]; l4.z = ll[2]; l4.w = ll[3];
    ((short4*)hi)[i] = h4;
    ((short4*)lo)[i] = l4;
}

// ---------- split-bf16 MFMA GEMM, 128x64 tile, XCD-panel swizzle, dbuf ----------
// terms bitmask: bit0 = add Al*Bh (loads Al), bit1 = add Ah*Bl (loads Bl).
// Q/K use 3 (both, selection-critical); V/O use 0 (plain bf16, additive error ~2e-3).
// mode 0: f32 row-major; mode 1: f32 split-heads; mode 2: bf16 hi/lo split-heads (scaled)
__global__ void __launch_bounds__(256) gemm_bf16s(
    const short* __restrict__ Ah, const short* __restrict__ Al,
    const short* __restrict__ Bh, const short* __restrict__ Bl,
    const float* __restrict__ bias, float* __restrict__ Cf,
    short* __restrict__ Ch, short* __restrict__ Cl, float scale, int mode, int terms)
{
    const int bid = blockIdx.x;               // 0..511
    const int xcd = bid & 7, slot = bid >> 3; // slot 0..63
    const int panel = xcd * 4 + (slot >> 4);  // 4 panels per XCD
    const int ncol  = slot & 15;
    const int tid = threadIdx.x, lane = tid & 63, wv = tid >> 6;
    const int wr = wv >> 1, wc = wv & 1;
    const int m0 = panel * 128 + wr * 64;
    const int n0 = ncol * 64 + wc * 32;
    const int lrow = lane & 15, lk = (lane >> 4) * 8;

    floatx4 acc[4][2];
#pragma unroll
    for (int i = 0; i < 4; ++i)
#pragma unroll
        for (int j = 0; j < 2; ++j) acc[i][j] = (floatx4){0.f, 0.f, 0.f, 0.f};

    auto ldfr = [&](int kk, short8x* pah, short8x* pal, short8x* pbh, short8x* pbl) {
#pragma unroll
        for (int mb = 0; mb < 4; ++mb) {
            size_t off = (size_t)(m0 + mb * 16 + lrow) * DD + kk + lk;
            pah[mb] = *(const short8x*)(Ah + off);
            if (terms & 1) pal[mb] = *(const short8x*)(Al + off);
        }
#pragma unroll
        for (int nb = 0; nb < 2; ++nb) {
            size_t off = (size_t)(n0 + nb * 16 + lrow) * DD + kk + lk;
            pbh[nb] = *(const short8x*)(Bh + off);
            if (terms & 2) pbl[nb] = *(const short8x*)(Bl + off);
        }
    };
    auto domfma = [&](short8x* pah, short8x* pal, short8x* pbh, short8x* pbl) {
#pragma unroll
        for (int mb = 0; mb < 4; ++mb)
#pragma unroll
            for (int nb = 0; nb < 2; ++nb) {
                acc[mb][nb] = __builtin_amdgcn_mfma_f32_16x16x32_bf16(pah[mb], pbh[nb], acc[mb][nb], 0, 0, 0);
                if (terms & 2)
                    acc[mb][nb] = __builtin_amdgcn_mfma_f32_16x16x32_bf16(pah[mb], pbl[nb], acc[mb][nb], 0, 0, 0);
                if (terms & 1)
                    acc[mb][nb] = __builtin_amdgcn_mfma_f32_16x16x32_bf16(pal[mb], pbh[nb], acc[mb][nb], 0, 0, 0);
            }
    };

    short8x A0[4], L0[4], B0[2], C0[2];
    short8x A1[4], L1[4], B1[2], C1[2];
    ldfr(0, A0, L0, B0, C0);
    for (int kk = 0; kk < DD; kk += 64) {
        ldfr(kk + 32, A1, L1, B1, C1);
        domfma(A0, L0, B0, C0);
        if (kk + 64 < DD) ldfr(kk + 64, A0, L0, B0, C0);
        domfma(A1, L1, B1, C1);
    }

#pragma unroll
    for (int mb = 0; mb < 4; ++mb)
#pragma unroll
        for (int nb = 0; nb < 2; ++nb) {
            int n = n0 + nb * 16 + lrow;
            float bv = bias[n];
#pragma unroll
            for (int j = 0; j < 4; ++j) {
                int m = m0 + mb * 16 + (lane >> 4) * 4 + j;
                float v = acc[mb][nb][j] + bv;
                if (mode == 0) {
                    Cf[(size_t)m * DD + n] = v;
                } else {
                    int b = m >> 11, t = m & (TT - 1), h = n >> 6, dh = n & (HD - 1);
                    size_t idx = (((size_t)b * NH + h) * TT + t) * HD + dh;
                    if (mode == 1) {
                        Cf[idx] = v;
                    } else {
                        v *= scale;
                        short hi16 = bf16_rne(v);
                        Ch[idx] = hi16;
                        Cl[idx] = bf16_rne(v - bf16_to_f(hi16));
                    }
                }
            }
        }
}

// ---------- f32 GEMM (fallback) ----------
__global__ void __launch_bounds__(256) gemm_xwt(
    const float* __restrict__ A, const float* __restrict__ W,
    const float* __restrict__ bias, float* __restrict__ C,
    int M, int N, int K, int split_heads)
{
    __shared__ float As[64][17];
    __shared__ float Ws[64][17];
    const int tid = threadIdx.x;
    const int tx = tid & 15, ty = tid >> 4;
    const int arow = blockIdx.y * 64, bcol = blockIdx.x * 64;
    float acc[4][4] = {};

    for (int k0 = 0; k0 < K; k0 += 16) {
        const int r = tid >> 2, c = (tid & 3) * 4;
        float4 a4 = *(const float4*)(A + (size_t)(arow + r) * K + k0 + c);
        As[r][c] = a4.x; As[r][c + 1] = a4.y; As[r][c + 2] = a4.z; As[r][c + 3] = a4.w;
        float4 w4 = *(const float4*)(W + (size_t)(bcol + r) * K + k0 + c);
        Ws[r][c] = w4.x; Ws[r][c + 1] = w4.y; Ws[r][c + 2] = w4.z; Ws[r][c + 3] = w4.w;
        __syncthreads();
#pragma unroll
        for (int k = 0; k < 16; ++k) {
            float a0 = As[ty * 4 + 0][k], a1 = As[ty * 4 + 1][k];
            float a2 = As[ty * 4 + 2][k], a3 = As[ty * 4 + 3][k];
            float w0 = Ws[tx * 4 + 0][k], w1 = Ws[tx * 4 + 1][k];
            float w2 = Ws[tx * 4 + 2][k], w3 = Ws[tx * 4 + 3][k];
            acc[0][0] += a0 * w0; acc[0][1] += a0 * w1; acc[0][2] += a0 * w2; acc[0][3] += a0 * w3;
            acc[1][0] += a1 * w0; acc[1][1] += a1 * w1; acc[1][2] += a1 * w2; acc[1][3] += a1 * w3;
            acc[2][0] += a2 * w0; acc[2][1] += a2 * w1; acc[2][2] += a2 * w2; acc[2][3] += a2 * w3;
            acc[3][0] += a3 * w0; acc[3][1] += a3 * w1; acc[3][2] += a3 * w2; acc[3][3] += a3 * w3;
        }
        __syncthreads();
    }

#pragma unroll
    for (int i = 0; i < 4; ++i) {
        int m = arow + ty * 4 + i;
#pragma unroll
        for (int j = 0; j < 4; ++j) {
            int n = bcol + tx * 4 + j;
            float v = acc[i][j] + bias[n];
            if (split_heads) {
                int b = m / TT, t = m % TT, h = n / HD, dh = n % HD;
                C[(((size_t)b * NH + h) * TT + t) * HD + dh] = v;
            } else {
                C[(size_t)m * N + n] = v;
            }
        }
    }
}

// ---------- MFMA attention with exact register-resident top-64 ----------
// XCD-swizzled 1D grid: each XCD owns 4 heads -> K/V stay L2-resident.
__global__ void __launch_bounds__(1024) attn_topk(
    const short* __restrict__ Qhi, const short* __restrict__ Qlo,
    const short* __restrict__ Khi, const short* __restrict__ Klo,
    const float* __restrict__ V, const uint32_t* __restrict__ Mt,
    const int* __restrict__ flags, short* __restrict__ Ohi,
    short* __restrict__ Olo, float* __restrict__ Of)
{
    __shared__ float s_S[2][QT][KT + 1];     // 32.9 KB (double-buffered)

    const int tid = threadIdx.x, lane = tid & 63, wv = tid >> 6;
    const int d = blockIdx.x;                // 0..4095, XCD = d & 7
    const int xcd = d & 7, chunk = d >> 3;
    const int bh = (xcd << 2) | (chunk >> 7);  // 4 heads per XCD
    const int qt = chunk & 127;
    const int b = bh >> 4, h = bh & 15;
    const int causal = flags[1];
    const size_t hb = (size_t)bh * (size_t)TT * HD;
    const int r0 = qt * QT;
    const int gq = r0 + wv;
    const float* __restrict__ Vh = V + hb;
    const float* __restrict__ Vl = Vh + lane;

    short8x qhi[2], qlo[2];
    {
        const size_t qoff = hb + (size_t)(r0 + (lane & 15)) * HD + (lane >> 4) * 8;
        qhi[0] = *(const short8x*)(Qhi + qoff);
        qhi[1] = *(const short8x*)(Qhi + qoff + 32);
        qlo[0] = *(const short8x*)(Qlo + qoff);
        qlo[1] = *(const short8x*)(Qlo + qoff + 32);
    }

    const uint32_t mwords = Mt[b * 64 + lane];

    uint32_t lgo[32];
#pragma unroll
    for (int i = 0; i < 32; ++i) lgo[i] = ORD_NEG;

    const int lastT = causal ? ((r0 + QT - 1) >> 8) : 7;

#pragma unroll
    for (int t = 0; t < 8; ++t) {
        if (t <= lastT) {
            const size_t koff = hb + (size_t)(t * KT + wv * 16 + (lane & 15)) * HD + (lane >> 4) * 8;
            short8x kh0 = *(const short8x*)(Khi + koff);
            short8x kh1 = *(const short8x*)(Khi + koff + 32);
            short8x kl0 = *(const short8x*)(Klo + koff);
            short8x kl1 = *(const short8x*)(Klo + koff + 32);
            floatx4 acc = {0.f, 0.f, 0.f, 0.f};
            acc = __builtin_amdgcn_mfma_f32_16x16x32_bf16(qhi[0], kh0, acc, 0, 0, 0);
            acc = __builtin_amdgcn_mfma_f32_16x16x32_bf16(qhi[0], kl0, acc, 0, 0, 0);
            acc = __builtin_amdgcn_mfma_f32_16x16x32_bf16(qlo[0], kh0, acc, 0, 0, 0);
            acc = __builtin_amdgcn_mfma_f32_16x16x32_bf16(qhi[1], kh1, acc, 0, 0, 0);
            acc = __builtin_amdgcn_mfma_f32_16x16x32_bf16(qhi[1], kl1, acc, 0, 0, 0);
            acc = __builtin_amdgcn_mfma_f32_16x16x32_bf16(qlo[1], kh1, acc, 0, 0, 0);
#pragma unroll
            for (int j = 0; j < 4; ++j)
                s_S[t & 1][(lane >> 4) * 4 + j][wv * 16 + (lane & 15)] = acc[j];
            __syncthreads();
#pragma unroll
            for (int j = 0; j < 4; ++j) {
                float sv = s_S[t & 1][wv][j * 64 + lane];
                int key = t * KT + j * 64 + lane;
                bool blocked = ((mwords >> (t * 4 + j)) & 1u) || (causal && key > gq);
                lgo[t * 4 + j] = blocked ? ORD_NEG : ord_u32(sv);
            }
        }
    }

    // ---- epilogue: exact top-64 select + softmax + sparse A*V ----
    uint32_t moL = 0;
#pragma unroll
    for (int i = 0; i < 32; ++i) {
        uint32_t u = lgo[i];
        moL = u > moL ? u : moL;
    }
    const uint32_t mo = dpp_wumax(moL);

    auto wcount = [&](uint32_t thrv) -> int {
        int c = 0;
#pragma unroll
        for (int i = 0; i < 32; ++i) c += (lgo[i] >= thrv) ? 1 : 0;
        return dpp_wsum(c);
    };

    float outv;
    if (mo == ORD_NEG) {
        // fully blocked row: reference softmax is uniform over ALL keys
        float a0 = 0.f, a1 = 0.f, a2 = 0.f, a3 = 0.f;
        for (int j = 0; j < TT; j += 4) {
            a0 += Vh[(j + 0) * HD + lane];
            a1 += Vh[(j + 1) * HD + lane];
            a2 += Vh[(j + 2) * HD + lane];
            a3 += Vh[(j + 3) * HD + lane];
        }
        outv = (a0 + a1 + a2 + a3) * (1.0f / TT);
    } else {
        const float mF = unord(mo);
        uint32_t thr = 0; uint32_t lo_b = 0, hi_b = 0; int done = 0;
        {
            uint32_t p1 = ord_u32(mF - 2.0f);
            int c1 = wcount(p1);
            if (c1 == TOPK) { thr = p1; done = 1; }
            else if (c1 > TOPK) { lo_b = p1; hi_b = mo; }
            else {
                uint32_t p2 = ord_u32(mF - 4.0f);
                int c2 = wcount(p2);
                if (c2 == TOPK) { thr = p2; done = 1; }
                else if (c2 > TOPK) { lo_b = p2; hi_b = p1; }
                else {
                    uint32_t p3 = ord_u32(mF - 15.0f);
                    int c3 = wcount(p3);
                    if (c3 <= TOPK) { thr = p3; done = 1; }  // <64 candidates: rest < e^-15
                    else { lo_b = p3; hi_b = p2; }
                }
            }
        }
        if (!done) {
            while (hi_b - lo_b > 1u) {
                uint32_t mid = lo_b + ((hi_b - lo_b) >> 1);
                int c = wcount(mid);
                if (c == TOPK) { lo_b = mid; break; }
                if (c > TOPK) lo_b = mid; else hi_b = mid;
            }
            thr = lo_b;
        }

        float Sp = 0.f;
#pragma unroll
        for (int i = 0; i < 32; ++i) {
            uint32_t u = lgo[i];
            float w = 0.f;
            if (u >= thr) w = __expf(unord(u) - mF);
            Sp += w;
            lgo[i] = (w > 0.f) ? __float_as_uint(w) : 0u;
        }
        const float S = dpp_fsum(Sp);

        // sparse A*V via ballot + ctz + readlane: key computed from (i, src),
        // SGPR-chain addressing, zero LDS, 4 rotating accumulators.
        float a0 = 0.f, a1 = 0.f, a2 = 0.f, a3 = 0.f;
#pragma unroll
        for (int i = 0; i < 32; ++i) {
            unsigned long long msk = __ballot(lgo[i] != 0u);
            const int kbase = ((i >> 2) * KT + (i & 3) * 64) * HD;
            while (msk) {
                int src = (int)__builtin_ctzll(msk);
                msk &= (msk - 1);
                float w = __uint_as_float((uint32_t)__builtin_amdgcn_readlane((int)lgo[i], src));
                float prod = w * Vl[kbase + src * HD];
                if ((i & 3) == 0) a0 += prod;
                else if ((i & 3) == 1) a1 += prod;
                else if ((i & 3) == 2) a2 += prod;
                else a3 += prod;
            }
        }
        outv = ((a0 + a1) + (a2 + a3)) / S;
    }
    const size_t oidx = ((size_t)b * TT + gq) * DD + h * HD + lane;
    if (Of) {
        Of[oidx] = outv;
    } else {
        short hi16 = bf16_rne(outv);
        Ohi[oidx] = hi16;
        if (Olo) Olo[oidx] = bf16_rne(outv - bf16_to_f(hi16));
    }
}

// ---------- launch ----------
extern "C" void kernel_launch(void* const* d_in, const int* in_sizes, int n_in,
                              void* d_out, int out_size, void* d_ws, size_t ws_size,
                              hipStream_t stream) {
    const float* x  = (const float*)d_in[0];
    const float* Wq = (const float*)d_in[1];
    const float* bq = (const float*)d_in[2];
    const float* Wk = (const float*)d_in[3];
    const float* bk = (const float*)d_in[4];
    const float* Wv = (const float*)d_in[5];
    const float* bv = (const float*)d_in[6];
    const float* Wo = (const float*)d_in[7];
    const float* bo = (const float*)d_in[8];
    const void*  maskp = d_in[9];
    const int*   causalp = (const int*)d_in[10];
    float* out = (float*)d_out;

    char* ws = (char*)d_ws;
    const size_t TEN  = (size_t)BB * TT * DD * sizeof(float);  // 16.78 MB
    const size_t HTEN = TEN / 2;
    const size_t WSZ  = (size_t)DD * DD * 2;                   // 2 MB bf16 weight
    const size_t NEED = 6 * TEN + 4096;

    const int nx4 = BB * TT * DD / 4, nw4 = DD * DD / 4;

    if (ws_size >= NEED) {
        float* Vf   = (float*)(ws);
        short* xh   = (short*)(ws + TEN);
        short* xl   = (short*)(ws + TEN + HTEN);
        short* Qhi  = (short*)(ws + 2 * TEN);
        short* Qlo  = (short*)(ws + 2 * TEN + HTEN);
        short* Khi  = (short*)(ws + 3 * TEN);
        short* Klo  = (short*)(ws + 3 * TEN + HTEN);
        short* Ohi  = (short*)(ws + 4 * TEN);
        char*  wb   = ws + 5 * TEN;
        short* wqh = (short*)(wb);            short* wql = (short*)(wb + WSZ);
        short* wkh = (short*)(wb + 2 * WSZ);  short* wkl = (short*)(wb + 3 * WSZ);
        short* wvh = (short*)(wb + 4 * WSZ);  short* wvl = (short*)(wb + 5 * WSZ);
        short* woh = (short*)(wb + 6 * WSZ);  short* wol = (short*)(wb + 7 * WSZ);
        int*      flags = (int*)(wb + 8 * WSZ);
        uint32_t* Mt    = (uint32_t*)(wb + 8 * WSZ + 256);

        build_flags<<<1, 1024, 0, stream>>>((const unsigned char*)maskp, causalp, flags, Mt);

        split_f32<<<(nx4 + 255) / 256, 256, 0, stream>>>(x, xh, xl, nx4, 1.0f);
        dim3 wg((nw4 + 255) / 256, 4);
        split_w4<<<wg, 256, 0, stream>>>(Wq, Wk, Wv, Wo,
                                         wqh, wql, wkh, wkl, wvh, wvl, woh, wol, nw4);

        gemm_bf16s<<<512, 256, 0, stream>>>(xh, xl, wqh, wql, bq, nullptr, Qhi, Qlo, 0.125f, 2, 3);
        gemm_bf16s<<<512, 256, 0, stream>>>(xh, xl, wkh, wkl, bk, nullptr, Khi, Klo, 1.0f, 2, 3);
        gemm_bf16s<<<512, 256, 0, stream>>>(xh, xl, wvh, wvl, bv, Vf, nullptr, nullptr, 1.0f, 1, 0);

        attn_topk<<<BB * NH * (TT / QT), 1024, 0, stream>>>(Qhi, Qlo, Khi, Klo, Vf, Mt, flags,
                                                            Ohi, nullptr, nullptr);

        gemm_bf16s<<<512, 256, 0, stream>>>(Ohi, Ohi, woh, wol, bo, out, nullptr, nullptr, 1.0f, 0, 0);
    } else {
        float* Qf  = (float*)(ws);
        float* Kf  = (float*)(ws + TEN);
        float* Vf  = (float*)(ws + 2 * TEN);
        float* O   = (float*)(ws + 3 * TEN);
        short* Qhi = (short*)(ws + 4 * TEN);
        short* Qlo = (short*)(ws + 4 * TEN + HTEN);
        short* Khi = (short*)(ws + 5 * TEN);
        short* Klo = (short*)(ws + 5 * TEN + HTEN);
        int*      flags = (int*)(ws + 6 * TEN);
        uint32_t* Mt    = (uint32_t*)(ws + 6 * TEN + 256);

        build_flags<<<1, 1024, 0, stream>>>((const unsigned char*)maskp, causalp, flags, Mt);
        dim3 g2(DD / 64, (BB * TT) / 64);
        gemm_xwt<<<g2, 256, 0, stream>>>(x, Wq, bq, Qf, BB * TT, DD, DD, 1);
        gemm_xwt<<<g2, 256, 0, stream>>>(x, Wk, bk, Kf, BB * TT, DD, DD, 1);
        gemm_xwt<<<g2, 256, 0, stream>>>(x, Wv, bv, Vf, BB * TT, DD, DD, 1);
        split_f32<<<(nx4 + 255) / 256, 256, 0, stream>>>(Qf, Qhi, Qlo, nx4, 0.125f);
        split_f32<<<(nx4 + 255) / 256, 256, 0, stream>>>(Kf, Khi, Klo, nx4, 1.0f);
        attn_topk<<<BB * NH * (TT / QT), 1024, 0, stream>>>(Qhi, Qlo, Khi, Klo, Vf, Mt, flags,
                                                            nullptr, nullptr, O);
        gemm_xwt<<<g2, 256, 0, stream>>>(O, Wo, bo, out, BB * TT, DD, DD, 0);
    }
}

// Round 10
// 680.321 us; speedup vs baseline: 1.2887x; 1.1128x over previous
//
#include <hip/hip_runtime.h>
#include <hip/hip_bf16.h>
#include <stdint.h>

#define BB 2
#define TT 2048
#define DD 1024
#define NH 16
#define HD 64
#define TOPK 64
#define NEGF (-3.402823466e38f)
#define ORD_NEG 0x00800000u  // ord_u32(NEGF)
#define QT 16                // q-rows per block (1 per wave)
#define KT 256               // keys per tile
#define SELCAP 96

typedef short short8x __attribute__((ext_vector_type(8)));
typedef float floatx4 __attribute__((ext_vector_type(4)));

// ---------- helpers ----------
__device__ __forceinline__ uint32_t ord_u32(float x) {
    uint32_t b = __float_as_uint(x);
    return (b & 0x80000000u) ? ~b : (b | 0x80000000u);
}
__device__ __forceinline__ float unord(uint32_t u) {
    uint32_t b = (u & 0x80000000u) ? (u ^ 0x80000000u) : ~u;
    return __uint_as_float(b);
}
__device__ __forceinline__ short bf16_rne(float x) {
    uint32_t u = __float_as_uint(x);
    u += 0x7FFFu + ((u >> 16) & 1u);
    return (short)(u >> 16);
}
__device__ __forceinline__ float bf16_to_f(short h) {
    return __uint_as_float(((uint32_t)(uint16_t)h) << 16);
}
__device__ __forceinline__ bool mask_at(const void* m, int mode, int idx) {
    if (mode == 0) return ((const int*)m)[idx] != 0;
    if (mode == 1) return ((const unsigned char*)m)[idx] != 0;
    return ((const float*)m)[idx] != 0.0f;
}

// ---------- DPP wave-64 reductions ----------
__device__ __forceinline__ int dpp_wsum(int v) {
    v += __builtin_amdgcn_update_dpp(0, v, 0x111, 0xf, 0xf, true);
    v += __builtin_amdgcn_update_dpp(0, v, 0x112, 0xf, 0xf, true);
    v += __builtin_amdgcn_update_dpp(0, v, 0x114, 0xf, 0xf, true);
    v += __builtin_amdgcn_update_dpp(0, v, 0x118, 0xf, 0xf, true);
    v += __builtin_amdgcn_update_dpp(0, v, 0x142, 0xa, 0xf, true);
    v += __builtin_amdgcn_update_dpp(0, v, 0x143, 0xc, 0xf, true);
    return __builtin_amdgcn_readlane(v, 63);
}
__device__ __forceinline__ uint32_t dpp_wumax(uint32_t v) {
    uint32_t t;
    t = (uint32_t)__builtin_amdgcn_update_dpp(0, (int)v, 0x111, 0xf, 0xf, true); v = v > t ? v : t;
    t = (uint32_t)__builtin_amdgcn_update_dpp(0, (int)v, 0x112, 0xf, 0xf, true); v = v > t ? v : t;
    t = (uint32_t)__builtin_amdgcn_update_dpp(0, (int)v, 0x114, 0xf, 0xf, true); v = v > t ? v : t;
    t = (uint32_t)__builtin_amdgcn_update_dpp(0, (int)v, 0x118, 0xf, 0xf, true); v = v > t ? v : t;
    t = (uint32_t)__builtin_amdgcn_update_dpp(0, (int)v, 0x142, 0xa, 0xf, true); v = v > t ? v : t;
    t = (uint32_t)__builtin_amdgcn_update_dpp(0, (int)v, 0x143, 0xc, 0xf, true); v = v > t ? v : t;
    return (uint32_t)__builtin_amdgcn_readlane((int)v, 63);
}
__device__ __forceinline__ float dpp_fsum(float v) {
    v += __uint_as_float((uint32_t)__builtin_amdgcn_update_dpp(0, (int)__float_as_uint(v), 0x111, 0xf, 0xf, true));
    v += __uint_as_float((uint32_t)__builtin_amdgcn_update_dpp(0, (int)__float_as_uint(v), 0x112, 0xf, 0xf, true));
    v += __uint_as_float((uint32_t)__builtin_amdgcn_update_dpp(0, (int)__float_as_uint(v), 0x114, 0xf, 0xf, true));
    v += __uint_as_float((uint32_t)__builtin_amdgcn_update_dpp(0, (int)__float_as_uint(v), 0x118, 0xf, 0xf, true));
    v += __uint_as_float((uint32_t)__builtin_amdgcn_update_dpp(0, (int)__float_as_uint(v), 0x142, 0xa, 0xf, true));
    v += __uint_as_float((uint32_t)__builtin_amdgcn_update_dpp(0, (int)__float_as_uint(v), 0x143, 0xc, 0xf, true));
    return __uint_as_float((uint32_t)__builtin_amdgcn_readlane((int)__float_as_uint(v), 63));
}

// ---------- mask detection + transposed bitmask build ----------
__global__ void __launch_bounds__(1024) build_flags(
    const unsigned char* raw, const int* causalp, int* flags, uint32_t* Mt)
{
    __shared__ int odd_nz, big, s_mode;
    __shared__ uint32_t smt[BB * 64];
    const int tid = threadIdx.x;
    if (tid == 0) { odd_nz = 0; big = 0; }
    if (tid < BB * 64) smt[tid] = 0;
    __syncthreads();
    for (int i = tid; i < BB * TT; i += 1024) {
        unsigned char c = raw[i];
        if ((i & 3) && c) atomicOr(&odd_nz, 1);
        if (c > 1) atomicOr(&big, 1);
    }
    __syncthreads();
    if (tid == 0) {
        int mode = odd_nz ? (big ? 2 : 1) : 0;
        s_mode = mode;
        flags[0] = mode;
        flags[1] = (causalp[0] != 0) ? 1 : 0;
    }
    __syncthreads();
    const int mode = s_mode;
    const int w = tid >> 3, g = tid & 7;
    const int bb = w >> 6, l = w & 63;
    uint32_t bits = 0;
#pragma unroll
    for (int si = 0; si < 4; ++si) {
        int s = g * 4 + si;
        if (mask_at(raw, mode, bb * TT + l + 64 * s)) bits |= (1u << s);
    }
    if (bits) atomicOr(&smt[w], bits);
    __syncthreads();
    if (tid < BB * 64) Mt[tid] = smt[tid];
}

// ---------- f32 -> (hi, lo) bf16 split (with scale) ----------
__global__ void __launch_bounds__(256) split_f32(
    const float* __restrict__ in, short* __restrict__ hi, short* __restrict__ lo,
    int n4, float scale)
{
    int i = blockIdx.x * blockDim.x + threadIdx.x;
    if (i >= n4) return;
    float4 v = ((const float4*)in)[i];
    float f[4] = {v.x * scale, v.y * scale, v.z * scale, v.w * scale};
    short hh[4], ll[4];
#pragma unroll
    for (int j = 0; j < 4; ++j) {
        hh[j] = bf16_rne(f[j]);
        ll[j] = bf16_rne(f[j] - bf16_to_f(hh[j]));
    }
    short4 h4; h4.x = hh[0]; h4.y = hh[1]; h4.z = hh[2]; h4.w = hh[3];
    short4 l4; l4.x = ll[0]; l4.y = ll[1]; l4.z = ll[2]; l4.w = ll[3];
    ((short4*)hi)[i] = h4;
    ((short4*)lo)[i] = l4;
}

// ---------- 4 weights split in one launch ----------
__global__ void __launch_bounds__(256) split_w4(
    const float* __restrict__ W0, const float* __restrict__ W1,
    const float* __restrict__ W2, const float* __restrict__ W3,
    short* __restrict__ h0, short* __restrict__ l0, short* __restrict__ h1, short* __restrict__ l1,
    short* __restrict__ h2, short* __restrict__ l2, short* __restrict__ h3, short* __restrict__ l3,
    int n4)
{
    int i = blockIdx.x * blockDim.x + threadIdx.x;
    if (i >= n4) return;
    const int w = blockIdx.y;
    const float* in = (w == 0) ? W0 : (w == 1) ? W1 : (w == 2) ? W2 : W3;
    short* hi = (w == 0) ? h0 : (w == 1) ? h1 : (w == 2) ? h2 : h3;
    short* lo = (w == 0) ? l0 : (w == 1) ? l1 : (w == 2) ? l2 : l3;
    float4 v = ((const float4*)in)[i];
    float f[4] = {v.x, v.y, v.z, v.w};
    short hh[4], ll[4];
#pragma unroll
    for (int j = 0; j < 4; ++j) {
        hh[j] = bf16_rne(f[j]);
        ll[j] = bf16_rne(f[j] - bf16_to_f(hh[j]));
    }
    short4 h4; h4.x = hh[0]; h4.y = hh[1]; h4.z = hh[2]; h4.w = hh[3];
    short4 l4; l4.x = ll[0]; l4.y = ll[1]; l4.z = ll[2]; l4.w = ll[3];
    ((short4*)hi)[i] = h4;
    ((short4*)lo)[i] = l4;
}

// ---------- split-bf16 MFMA GEMM, 128x64 tile, XCD-panel swizzle, dbuf ----------
// terms bitmask: bit0 = add Al*Bh (loads Al), bit1 = add Ah*Bl (loads Bl).
// Q/K use 3 (selection-critical); V/O use 0 (plain bf16, additive error ~2e-3).
__global__ void __launch_bounds__(256) gemm_bf16s(
    const short* __restrict__ Ah, const short* __restrict__ Al,
    const short* __restrict__ Bh, const short* __restrict__ Bl,
    const float* __restrict__ bias, float* __restrict__ Cf,
    short* __restrict__ Ch, short* __restrict__ Cl, float scale, int mode, int terms)
{
    const int bid = blockIdx.x;               // 0..511
    const int xcd = bid & 7, slot = bid >> 3; // slot 0..63
    const int panel = xcd * 4 + (slot >> 4);  // 4 panels per XCD
    const int ncol  = slot & 15;
    const int tid = threadIdx.x, lane = tid & 63, wv = tid >> 6;
    const int wr = wv >> 1, wc = wv & 1;
    const int m0 = panel * 128 + wr * 64;
    const int n0 = ncol * 64 + wc * 32;
    const int lrow = lane & 15, lk = (lane >> 4) * 8;

    floatx4 acc[4][2];
#pragma unroll
    for (int i = 0; i < 4; ++i)
#pragma unroll
        for (int j = 0; j < 2; ++j) acc[i][j] = (floatx4){0.f, 0.f, 0.f, 0.f};

    auto ldfr = [&](int kk, short8x* pah, short8x* pal, short8x* pbh, short8x* pbl) {
#pragma unroll
        for (int mb = 0; mb < 4; ++mb) {
            size_t off = (size_t)(m0 + mb * 16 + lrow) * DD + kk + lk;
            pah[mb] = *(const short8x*)(Ah + off);
            if (terms & 1) pal[mb] = *(const short8x*)(Al + off);
        }
#pragma unroll
        for (int nb = 0; nb < 2; ++nb) {
            size_t off = (size_t)(n0 + nb * 16 + lrow) * DD + kk + lk;
            pbh[nb] = *(const short8x*)(Bh + off);
            if (terms & 2) pbl[nb] = *(const short8x*)(Bl + off);
        }
    };
    auto domfma = [&](short8x* pah, short8x* pal, short8x* pbh, short8x* pbl) {
#pragma unroll
        for (int mb = 0; mb < 4; ++mb)
#pragma unroll
            for (int nb = 0; nb < 2; ++nb) {
                acc[mb][nb] = __builtin_amdgcn_mfma_f32_16x16x32_bf16(pah[mb], pbh[nb], acc[mb][nb], 0, 0, 0);
                if (terms & 2)
                    acc[mb][nb] = __builtin_amdgcn_mfma_f32_16x16x32_bf16(pah[mb], pbl[nb], acc[mb][nb], 0, 0, 0);
                if (terms & 1)
                    acc[mb][nb] = __builtin_amdgcn_mfma_f32_16x16x32_bf16(pal[mb], pbh[nb], acc[mb][nb], 0, 0, 0);
            }
    };

    short8x A0[4], L0[4], B0[2], C0[2];
    short8x A1[4], L1[4], B1[2], C1[2];
    ldfr(0, A0, L0, B0, C0);
    for (int kk = 0; kk < DD; kk += 64) {
        ldfr(kk + 32, A1, L1, B1, C1);
        domfma(A0, L0, B0, C0);
        if (kk + 64 < DD) ldfr(kk + 64, A0, L0, B0, C0);
        domfma(A1, L1, B1, C1);
    }

#pragma unroll
    for (int mb = 0; mb < 4; ++mb)
#pragma unroll
        for (int nb = 0; nb < 2; ++nb) {
            int n = n0 + nb * 16 + lrow;
            float bv = bias[n];
#pragma unroll
            for (int j = 0; j < 4; ++j) {
                int m = m0 + mb * 16 + (lane >> 4) * 4 + j;
                float v = acc[mb][nb][j] + bv;
                if (mode == 0) {
                    Cf[(size_t)m * DD + n] = v;
                } else {
                    int b = m >> 11, t = m & (TT - 1), h = n >> 6, dh = n & (HD - 1);
                    size_t idx = (((size_t)b * NH + h) * TT + t) * HD + dh;
                    if (mode == 1) {
                        Cf[idx] = v;
                    } else {
                        v *= scale;
                        short hi16 = bf16_rne(v);
                        Ch[idx] = hi16;
                        Cl[idx] = bf16_rne(v - bf16_to_f(hi16));
                    }
                }
            }
        }
}

// ---------- f32 GEMM (fallback) ----------
__global__ void __launch_bounds__(256) gemm_xwt(
    const float* __restrict__ A, const float* __restrict__ W,
    const float* __restrict__ bias, float* __restrict__ C,
    int M, int N, int K, int split_heads)
{
    __shared__ float As[64][17];
    __shared__ float Ws[64][17];
    const int tid = threadIdx.x;
    const int tx = tid & 15, ty = tid >> 4;
    const int arow = blockIdx.y * 64, bcol = blockIdx.x * 64;
    float acc[4][4] = {};

    for (int k0 = 0; k0 < K; k0 += 16) {
        const int r = tid >> 2, c = (tid & 3) * 4;
        float4 a4 = *(const float4*)(A + (size_t)(arow + r) * K + k0 + c);
        As[r][c] = a4.x; As[r][c + 1] = a4.y; As[r][c + 2] = a4.z; As[r][c + 3] = a4.w;
        float4 w4 = *(const float4*)(W + (size_t)(bcol + r) * K + k0 + c);
        Ws[r][c] = w4.x; Ws[r][c + 1] = w4.y; Ws[r][c + 2] = w4.z; Ws[r][c + 3] = w4.w;
        __syncthreads();
#pragma unroll
        for (int k = 0; k < 16; ++k) {
            float a0 = As[ty * 4 + 0][k], a1 = As[ty * 4 + 1][k];
            float a2 = As[ty * 4 + 2][k], a3 = As[ty * 4 + 3][k];
            float w0 = Ws[tx * 4 + 0][k], w1 = Ws[tx * 4 + 1][k];
            float w2 = Ws[tx * 4 + 2][k], w3 = Ws[tx * 4 + 3][k];
            acc[0][0] += a0 * w0; acc[0][1] += a0 * w1; acc[0][2] += a0 * w2; acc[0][3] += a0 * w3;
            acc[1][0] += a1 * w0; acc[1][1] += a1 * w1; acc[1][2] += a1 * w2; acc[1][3] += a1 * w3;
            acc[2][0] += a2 * w0; acc[2][1] += a2 * w1; acc[2][2] += a2 * w2; acc[2][3] += a2 * w3;
            acc[3][0] += a3 * w0; acc[3][1] += a3 * w1; acc[3][2] += a3 * w2; acc[3][3] += a3 * w3;
        }
        __syncthreads();
    }

#pragma unroll
    for (int i = 0; i < 4; ++i) {
        int m = arow + ty * 4 + i;
#pragma unroll
        for (int j = 0; j < 4; ++j) {
            int n = bcol + tx * 4 + j;
            float v = acc[i][j] + bias[n];
            if (split_heads) {
                int b = m / TT, t = m % TT, h = n / HD, dh = n % HD;
                C[(((size_t)b * NH + h) * TT + t) * HD + dh] = v;
            } else {
                C[(size_t)m * N + n] = v;
            }
        }
    }
}

// ---------- MFMA attention with exact register-resident top-64 ----------
// XCD-swizzled 1D grid: each XCD owns 4 heads -> K/V stay L2-resident.
__global__ void __launch_bounds__(1024) attn_topk(
    const short* __restrict__ Qhi, const short* __restrict__ Qlo,
    const short* __restrict__ Khi, const short* __restrict__ Klo,
    const float* __restrict__ V, const uint32_t* __restrict__ Mt,
    const int* __restrict__ flags, short* __restrict__ Ohi,
    short* __restrict__ Olo, float* __restrict__ Of)
{
    __shared__ float s_S[2][QT][KT + 1];     // 32.9 KB (double-buffered)
    __shared__ int2  s_sel[QT][SELCAP];      // packed (key<<6, w bits)

    const int tid = threadIdx.x, lane = tid & 63, wv = tid >> 6;
    const int d = blockIdx.x;                // 0..4095, XCD = d & 7
    const int xcd = d & 7, chunk = d >> 3;
    const int bh = (xcd << 2) | (chunk >> 7);  // 4 heads per XCD
    const int qt = chunk & 127;
    const int b = bh >> 4, h = bh & 15;
    const int causal = flags[1];
    const size_t hb = (size_t)bh * (size_t)TT * HD;
    const int r0 = qt * QT;
    const int gq = r0 + wv;
    const float* __restrict__ Vh = V + hb;
    const float* __restrict__ Vl = Vh + lane;

    short8x qhi[2], qlo[2];
    {
        const size_t qoff = hb + (size_t)(r0 + (lane & 15)) * HD + (lane >> 4) * 8;
        qhi[0] = *(const short8x*)(Qhi + qoff);
        qhi[1] = *(const short8x*)(Qhi + qoff + 32);
        qlo[0] = *(const short8x*)(Qlo + qoff);
        qlo[1] = *(const short8x*)(Qlo + qoff + 32);
    }

    const uint32_t mwords = Mt[b * 64 + lane];

    uint32_t lgo[32];
#pragma unroll
    for (int i = 0; i < 32; ++i) lgo[i] = ORD_NEG;

    const int lastT = causal ? ((r0 + QT - 1) >> 8) : 7;

#pragma unroll
    for (int t = 0; t < 8; ++t) {
        if (t <= lastT) {
            const size_t koff = hb + (size_t)(t * KT + wv * 16 + (lane & 15)) * HD + (lane >> 4) * 8;
            short8x kh0 = *(const short8x*)(Khi + koff);
            short8x kh1 = *(const short8x*)(Khi + koff + 32);
            short8x kl0 = *(const short8x*)(Klo + koff);
            short8x kl1 = *(const short8x*)(Klo + koff + 32);
            floatx4 acc = {0.f, 0.f, 0.f, 0.f};
            acc = __builtin_amdgcn_mfma_f32_16x16x32_bf16(qhi[0], kh0, acc, 0, 0, 0);
            acc = __builtin_amdgcn_mfma_f32_16x16x32_bf16(qhi[0], kl0, acc, 0, 0, 0);
            acc = __builtin_amdgcn_mfma_f32_16x16x32_bf16(qlo[0], kh0, acc, 0, 0, 0);
            acc = __builtin_amdgcn_mfma_f32_16x16x32_bf16(qhi[1], kh1, acc, 0, 0, 0);
            acc = __builtin_amdgcn_mfma_f32_16x16x32_bf16(qhi[1], kl1, acc, 0, 0, 0);
            acc = __builtin_amdgcn_mfma_f32_16x16x32_bf16(qlo[1], kh1, acc, 0, 0, 0);
#pragma unroll
            for (int j = 0; j < 4; ++j)
                s_S[t & 1][(lane >> 4) * 4 + j][wv * 16 + (lane & 15)] = acc[j];
            __syncthreads();
#pragma unroll
            for (int j = 0; j < 4; ++j) {
                float sv = s_S[t & 1][wv][j * 64 + lane];
                int key = t * KT + j * 64 + lane;
                bool blocked = ((mwords >> (t * 4 + j)) & 1u) || (causal && key > gq);
                lgo[t * 4 + j] = blocked ? ORD_NEG : ord_u32(sv);
            }
        }
    }

    // ---- epilogue: exact top-64 select + softmax + sparse A*V ----
    uint32_t moL = 0;
#pragma unroll
    for (int i = 0; i < 32; ++i) {
        uint32_t u = lgo[i];
        moL = u > moL ? u : moL;
    }
    const uint32_t mo = dpp_wumax(moL);

    auto wcount = [&](uint32_t thrv) -> int {
        int c = 0;
#pragma unroll
        for (int i = 0; i < 32; ++i) c += (lgo[i] >= thrv) ? 1 : 0;
        return dpp_wsum(c);
    };

    float outv;
    if (mo == ORD_NEG) {
        // fully blocked row: reference softmax is uniform over ALL keys
        float a0 = 0.f, a1 = 0.f, a2 = 0.f, a3 = 0.f;
        for (int j = 0; j < TT; j += 4) {
            a0 += Vh[(j + 0) * HD + lane];
            a1 += Vh[(j + 1) * HD + lane];
            a2 += Vh[(j + 2) * HD + lane];
            a3 += Vh[(j + 3) * HD + lane];
        }
        outv = (a0 + a1 + a2 + a3) * (1.0f / TT);
    } else {
        const float mF = unord(mo);
        uint32_t thr = 0; uint32_t lo_b = 0, hi_b = 0; int done = 0;
        {
            uint32_t p1 = ord_u32(mF - 2.0f);
            int c1 = wcount(p1);
            if (c1 == TOPK) { thr = p1; done = 1; }
            else if (c1 > TOPK) { lo_b = p1; hi_b = mo; }
            else {
                uint32_t p2 = ord_u32(mF - 4.0f);
                int c2 = wcount(p2);
                if (c2 == TOPK) { thr = p2; done = 1; }
                else if (c2 > TOPK) { lo_b = p2; hi_b = p1; }
                else {
                    uint32_t p3 = ord_u32(mF - 15.0f);
                    int c3 = wcount(p3);
                    if (c3 <= TOPK) { thr = p3; done = 1; }  // <64 candidates: rest < e^-15
                    else { lo_b = p3; hi_b = p2; }
                }
            }
        }
        if (!done) {
            while (hi_b - lo_b > 1u) {
                uint32_t mid = lo_b + ((hi_b - lo_b) >> 1);
                int c = wcount(mid);
                if (c == TOPK) { lo_b = mid; break; }
                if (c > TOPK) lo_b = mid; else hi_b = mid;
            }
            thr = lo_b;
        }

        float Sp = 0.f;
#pragma unroll
        for (int i = 0; i < 32; ++i) {
            uint32_t u = lgo[i];
            float w = 0.f;
            if (u >= thr) w = __expf(unord(u) - mF);
            Sp += w;
            lgo[i] = (w > 0.f) ? __float_as_uint(w) : 0u;
        }
        const float S = dpp_fsum(Sp);

        // ballot/mbcnt compaction into LDS (fixed-trip, no atomics)
        int base = 0;
#pragma unroll
        for (int i = 0; i < 32; ++i) {
            uint32_t wbits = lgo[i];
            unsigned long long msk = __ballot(wbits != 0);
            if (wbits) {
                int below = __builtin_amdgcn_mbcnt_hi((uint32_t)(msk >> 32),
                            __builtin_amdgcn_mbcnt_lo((uint32_t)msk, 0));
                int pos = base + below;
                if (pos < SELCAP) {
                    int keyoff = (((i >> 2) * KT + (i & 3) * 64 + lane) << 6);
                    s_sel[wv][pos] = make_int2(keyoff, (int)wbits);
                }
            }
            base += (int)__popcll(msk);
        }
        int cnt = base < SELCAP ? base : SELCAP;

        // sparse A*V: 4-wide batched scalar keys -> 4 independent loads in flight
        float acc = 0.f;
        int i2 = 0;
        for (; i2 + 4 <= cnt; i2 += 4) {
            int2 e0 = s_sel[wv][i2],     e1 = s_sel[wv][i2 + 1];
            int2 e2 = s_sel[wv][i2 + 2], e3 = s_sel[wv][i2 + 3];
            int k0 = __builtin_amdgcn_readfirstlane(e0.x);
            int k1 = __builtin_amdgcn_readfirstlane(e1.x);
            int k2 = __builtin_amdgcn_readfirstlane(e2.x);
            int k3 = __builtin_amdgcn_readfirstlane(e3.x);
            float w0 = __uint_as_float((uint32_t)__builtin_amdgcn_readfirstlane(e0.y));
            float w1 = __uint_as_float((uint32_t)__builtin_amdgcn_readfirstlane(e1.y));
            float w2 = __uint_as_float((uint32_t)__builtin_amdgcn_readfirstlane(e2.y));
            float w3 = __uint_as_float((uint32_t)__builtin_amdgcn_readfirstlane(e3.y));
            acc += w0 * Vl[k0];
            acc += w1 * Vl[k1];
            acc += w2 * Vl[k2];
            acc += w3 * Vl[k3];
        }
        for (; i2 < cnt; ++i2) {
            int2 e = s_sel[wv][i2];
            int k = __builtin_amdgcn_readfirstlane(e.x);
            float w = __uint_as_float((uint32_t)__builtin_amdgcn_readfirstlane(e.y));
            acc += w * Vl[k];
        }
        outv = acc / S;
    }
    const size_t oidx = ((size_t)b * TT + gq) * DD + h * HD + lane;
    if (Of) {
        Of[oidx] = outv;
    } else {
        short hi16 = bf16_rne(outv);
        Ohi[oidx] = hi16;
        if (Olo) Olo[oidx] = bf16_rne(outv - bf16_to_f(hi16));
    }
}

// ---------- launch ----------
extern "C" void kernel_launch(void* const* d_in, const int* in_sizes, int n_in,
                              void* d_out, int out_size, void* d_ws, size_t ws_size,
                              hipStream_t stream) {
    const float* x  = (const float*)d_in[0];
    const float* Wq = (const float*)d_in[1];
    const float* bq = (const float*)d_in[2];
    const float* Wk = (const float*)d_in[3];
    const float* bk = (const float*)d_in[4];
    const float* Wv = (const float*)d_in[5];
    const float* bv = (const float*)d_in[6];
    const float* Wo = (const float*)d_in[7];
    const float* bo = (const float*)d_in[8];
    const void*  maskp = d_in[9];
    const int*   causalp = (const int*)d_in[10];
    float* out = (float*)d_out;

    char* ws = (char*)d_ws;
    const size_t TEN  = (size_t)BB * TT * DD * sizeof(float);  // 16.78 MB
    const size_t HTEN = TEN / 2;
    const size_t WSZ  = (size_t)DD * DD * 2;                   // 2 MB bf16 weight
    const size_t NEED = 6 * TEN + 4096;

    const int nx4 = BB * TT * DD / 4, nw4 = DD * DD / 4;

    if (ws_size >= NEED) {
        float* Vf   = (float*)(ws);
        short* xh   = (short*)(ws + TEN);
        short* xl   = (short*)(ws + TEN + HTEN);
        short* Qhi  = (short*)(ws + 2 * TEN);
        short* Qlo  = (short*)(ws + 2 * TEN + HTEN);
        short* Khi  = (short*)(ws + 3 * TEN);
        short* Klo  = (short*)(ws + 3 * TEN + HTEN);
        short* Ohi  = (short*)(ws + 4 * TEN);
        char*  wb   = ws + 5 * TEN;
        short* wqh = (short*)(wb);            short* wql = (short*)(wb + WSZ);
        short* wkh = (short*)(wb + 2 * WSZ);  short* wkl = (short*)(wb + 3 * WSZ);
        short* wvh = (short*)(wb + 4 * WSZ);  short* wvl = (short*)(wb + 5 * WSZ);
        short* woh = (short*)(wb + 6 * WSZ);  short* wol = (short*)(wb + 7 * WSZ);
        int*      flags = (int*)(wb + 8 * WSZ);
        uint32_t* Mt    = (uint32_t*)(wb + 8 * WSZ + 256);

        build_flags<<<1, 1024, 0, stream>>>((const unsigned char*)maskp, causalp, flags, Mt);

        split_f32<<<(nx4 + 255) / 256, 256, 0, stream>>>(x, xh, xl, nx4, 1.0f);
        dim3 wg((nw4 + 255) / 256, 4);
        split_w4<<<wg, 256, 0, stream>>>(Wq, Wk, Wv, Wo,
                                         wqh, wql, wkh, wkl, wvh, wvl, woh, wol, nw4);

        gemm_bf16s<<<512, 256, 0, stream>>>(xh, xl, wqh, wql, bq, nullptr, Qhi, Qlo, 0.125f, 2, 3);
        gemm_bf16s<<<512, 256, 0, stream>>>(xh, xl, wkh, wkl, bk, nullptr, Khi, Klo, 1.0f, 2, 3);
        gemm_bf16s<<<512, 256, 0, stream>>>(xh, xl, wvh, wvl, bv, Vf, nullptr, nullptr, 1.0f, 1, 0);

        attn_topk<<<BB * NH * (TT / QT), 1024, 0, stream>>>(Qhi, Qlo, Khi, Klo, Vf, Mt, flags,
                                                            Ohi, nullptr, nullptr);

        gemm_bf16s<<<512, 256, 0, stream>>>(Ohi, Ohi, woh, wol, bo, out, nullptr, nullptr, 1.0f, 0, 0);
    } else {
        float* Qf  = (float*)(ws);
        float* Kf  = (float*)(ws + TEN);
        float* Vf  = (float*)(ws + 2 * TEN);
        float* O   = (float*)(ws + 3 * TEN);
        short* Qhi = (short*)(ws + 4 * TEN);
        short* Qlo = (short*)(ws + 4 * TEN + HTEN);
        short* Khi = (short*)(ws + 5 * TEN);
        short* Klo = (short*)(ws + 5 * TEN + HTEN);
        int*      flags = (int*)(ws + 6 * TEN);
        uint32_t* Mt    = (uint32_t*)(ws + 6 * TEN + 256);

        build_flags<<<1, 1024, 0, stream>>>((const unsigned char*)maskp, causalp, flags, Mt);
        dim3 g2(DD / 64, (BB * TT) / 64);
        gemm_xwt<<<g2, 256, 0, stream>>>(x, Wq, bq, Qf, BB * TT, DD, DD, 1);
        gemm_xwt<<<g2, 256, 0, stream>>>(x, Wk, bk, Kf, BB * TT, DD, DD, 1);
        gemm_xwt<<<g2, 256, 0, stream>>>(x, Wv, bv, Vf, BB * TT, DD, DD, 1);
        split_f32<<<(nx4 + 255) / 256, 256, 0, stream>>>(Qf, Qhi, Qlo, nx4, 0.125f);
        split_f32<<<(nx4 + 255) / 256, 256, 0, stream>>>(Kf, Khi, Klo, nx4, 1.0f);
        attn_topk<<<BB * NH * (TT / QT), 1024, 0, stream>>>(Qhi, Qlo, Khi, Klo, Vf, Mt, flags,
                                                            nullptr, nullptr, O);
        gemm_xwt<<<g2, 256, 0, stream>>>(O, Wo, bo, out, BB * TT, DD, DD, 0);
    }
}